// Round 7
// baseline (46403.635 us; speedup 1.0000x reference)
//
#include <hip/hip_runtime.h>

// ---------------------------------------------------------------------------
// Adaptive-attention LSTM decoder (B=128, P=49, D=E=A=512, V=10000, T=50).
//  * Persistent scan: 64 co-resident blocks, 5 phases/step, fence-free grid
//    barriers (atomic counter + vmcnt(0) drain of write-through stores).
//  * Coherence: rotating inter-phase buffers (fresh addresses) + write-through
//    (sc0 sc1) stores; staging loads use bypass cache policy (aux=0x11).
//  * DEEP staging: full 128KB A-matrix per stage, 32 global_load_lds in
//    flight per wave, single drain -> ~8x per-block stream rate vs chunked.
//  * Hybrid parallelism: big weights col-parallel (R=1, L2-resident);
//    small-weight chains (s2->sen, ht->hid, chh->wp) row-parallel, fused.
//  * LSTM cell states m1/m2 in registers; g2p partials parked in registers.
// ---------------------------------------------------------------------------

typedef unsigned short u16;
typedef unsigned long long ull;
typedef short bf16x8 __attribute__((ext_vector_type(8)));
typedef float f32x4 __attribute__((ext_vector_type(4)));

#define MFMA16(a, b, c) __builtin_amdgcn_mfma_f32_16x16x32_bf16(a, b, c, 0, 0, 0)
#define NBLK 64

__device__ __forceinline__ u16 f2bf(float f) {
    union { float f; unsigned u; } v; v.f = f;
    return (u16)((v.u + 0x7fffu + ((v.u >> 16) & 1u)) >> 16);
}
__device__ __forceinline__ float bf2f(u16 h) {
    union { unsigned u; float f; } v; v.u = ((unsigned)h) << 16; return v.f;
}
__device__ __forceinline__ float sigm(float x) {
    x = fminf(fmaxf(x, -30.f), 30.f);
    return 1.f / (1.f + __expf(-x));
}
__device__ __forceinline__ float tanh_(float x) {
    x = fminf(fmaxf(x, -15.f), 15.f);
    float e = __expf(2.f * x);
    return (e - 1.f) / (e + 1.f);
}

// ---- write-through (reach LLC) stores; drained by vmcnt(0) at barrier ----
__device__ __forceinline__ void st16(u16* p, u16 v) {
    asm volatile("global_store_short %0, %1, off sc0 sc1" :: "v"(p), "v"((unsigned)v) : "memory");
}
__device__ __forceinline__ void st32f(float* p, float v) {
    asm volatile("global_store_dword %0, %1, off sc0 sc1" :: "v"(p), "v"(v) : "memory");
}
__device__ __forceinline__ void st64u(u16* p, ull v) {
    asm volatile("global_store_dwordx2 %0, %1, off sc0 sc1" :: "v"(p), "v"(v) : "memory");
}

// Fence-free grid barrier: drain own write-through stores, count arrivals.
__device__ __forceinline__ void grid_barrier(int* bar, int idx) {
    asm volatile("s_waitcnt vmcnt(0)" ::: "memory");
    __syncthreads();
    if (threadIdx.x == 0) {
        __hip_atomic_fetch_add(&bar[idx], 1, __ATOMIC_RELAXED, __HIP_MEMORY_SCOPE_AGENT);
        while (__hip_atomic_load(&bar[idx], __ATOMIC_RELAXED, __HIP_MEMORY_SCOPE_AGENT) < NBLK)
            __builtin_amdgcn_s_sleep(1);
    }
    __syncthreads();
    asm volatile("" ::: "memory");
}

// ---------------------------------------------------------------------------
// Deep LDS staging: ROWS x 512 bf16 (ROWS*1KB), XOR-swizzled via SOURCE addr.
// One global_load_lds instruction per row (64 lanes x 16B = 1024B = 1 row);
// ALL issued before a single drain -> ROWS/4 outstanding per wave.
// aux=0x11 (SC0|SC1): coherent bypass, no L2 allocation (rotation keeps
// correctness even if the encoding differs).
template<int ROWS>
__device__ __forceinline__ void stageR(u16* lds, const u16* __restrict__ A) {
    const int tid = threadIdx.x;
    const int w = tid >> 6, lane = tid & 63;
    constexpr int RPW = ROWS / 4;
    __syncthreads();   // protect previous LDS readers
#pragma unroll
    for (int i = 0; i < RPW; ++i) {
        int row = w * RPW + i;
        const u16* src = A + (size_t)row * 512 + ((lane ^ (row & 7)) << 3);
        u16* dst = lds + row * 512;   // wave-uniform; lane l writes dst + l*16B
        __builtin_amdgcn_global_load_lds(
            (const __attribute__((address_space(1))) void*)src,
            (__attribute__((address_space(3))) void*)dst, 16, 0, 0x11);
    }
    asm volatile("s_waitcnt vmcnt(0)" ::: "memory");
    __syncthreads();
}

__device__ __forceinline__ bf16x8 ldsF(const u16* lds, int row, int kk) {
    int c16 = kk >> 3;
    return *(const bf16x8*)(lds + row * 512 + ((c16 ^ (row & 7)) << 3));
}

// Col-parallel compute over a staged 128x512 A: 4 waves x 32 rows, NT n-tiles.
template<int NT>
__device__ __forceinline__ void compF(const u16* lds, const u16* __restrict__ W,
                                      int ldw, int koff, int wrow0, f32x4 acc[2][NT]) {
    const int tid = threadIdx.x;
    const int lane = tid & 63, r = lane & 15, lg = lane >> 4;
    const int m_base = (tid >> 6) * 32;
    for (int k0 = 0; k0 < 512; k0 += 32) {
        int kk = k0 + lg * 8;
        bf16x8 a0 = ldsF(lds, m_base + r, kk);
        bf16x8 a1 = ldsF(lds, m_base + 16 + r, kk);
#pragma unroll
        for (int j = 0; j < NT; ++j) {
            bf16x8 wf = *(const bf16x8*)(W + (size_t)(wrow0 + j * 16 + r) * ldw + koff + kk);
            acc[0][j] = MFMA16(a0, wf, acc[0][j]);
            acc[1][j] = MFMA16(a1, wf, acc[1][j]);
        }
    }
}

// Row-parallel fused chain on 64 rows [r0, r0+64):
//  V=0: s2 = relu(A@W1^T+b1) -> OB bf16 + LDS;  O2 = s2@W2^T+b2 -> f32
//  V=1: ht = tanh(A@W1^T+b1) -> OF f32 + LDS;   O2 = ht@W2^T+b2 -> f32
//  V=2: att = tanh(A@W1^T+b1) -> OB bf16 (no GEMM2)
template<int V>
__device__ __forceinline__ void chain64(int r0, const u16* SRC,
        const u16* __restrict__ W1, const float* __restrict__ b1,
        const u16* __restrict__ W2, const float* __restrict__ b2,
        u16* OB, float* OF, float* O2, u16* lds) {
    u16* ldsB = lds + 32768;
    const int tid = threadIdx.x;
    const int w = tid >> 6, lane = tid & 63, r = lane & 15, lg = lane >> 4;
    stageR<64>(lds, SRC + (size_t)r0 * 512);
#pragma unroll
    for (int half = 0; half < 2; ++half) {
        f32x4 acc[16] = {};
        for (int k0 = 0; k0 < 512; k0 += 32) {
            int kk = k0 + lg * 8;
            bf16x8 a = ldsF(lds, w * 16 + r, kk);
#pragma unroll
            for (int j = 0; j < 16; ++j) {
                bf16x8 wf = *(const bf16x8*)(W1 + (size_t)(half * 256 + j * 16 + r) * 512 + kk);
                acc[j] = MFMA16(a, wf, acc[j]);
            }
        }
#pragma unroll
        for (int j = 0; j < 16; ++j)
#pragma unroll
            for (int reg = 0; reg < 4; ++reg) {
                int lrow = w * 16 + lg * 4 + reg;
                int col = half * 256 + j * 16 + r;
                float v = acc[j][reg] + b1[col];
                v = (V == 0) ? fmaxf(v, 0.f) : tanh_(v);
                u16 hv = f2bf(v);
                int row = r0 + lrow;
                if (V == 0) st16(OB + (size_t)row * 512 + col, hv);
                if (V == 1) st32f(OF + (size_t)row * 512 + col, v);
                if (V == 2) st16(OB + (size_t)row * 512 + col, hv);
                if (V < 2) ldsB[lrow * 512 + (((col >> 3) ^ (lrow & 7)) << 3) + (col & 7)] = hv;
            }
    }
    if (V == 2) return;
    __syncthreads();
#pragma unroll
    for (int half = 0; half < 2; ++half) {
        f32x4 acc[16] = {};
        for (int k0 = 0; k0 < 512; k0 += 32) {
            int kk = k0 + lg * 8;
            bf16x8 a = ldsF(ldsB, w * 16 + r, kk);
#pragma unroll
            for (int j = 0; j < 16; ++j) {
                bf16x8 wf = *(const bf16x8*)(W2 + (size_t)(half * 256 + j * 16 + r) * 512 + kk);
                acc[j] = MFMA16(a, wf, acc[j]);
            }
        }
#pragma unroll
        for (int j = 0; j < 16; ++j)
#pragma unroll
            for (int reg = 0; reg < 4; ++reg) {
                int lrow = w * 16 + lg * 4 + reg;
                int col = half * 256 + j * 16 + r;
                st32f(O2 + (size_t)(r0 + lrow) * 512 + col, acc[j][reg] + b2[col]);
            }
    }
}

// Plain-global-A gemm (pre/post kernels only).
__device__ __forceinline__ void gemm_2x4(const u16* __restrict__ A0, const u16* __restrict__ A1,
                                         int asplit, int lda0, int lda1,
                                         const u16* __restrict__ W, int ldw, int K,
                                         int m_base, int n_base, int nt, f32x4 acc[2][4]) {
    const int lane = threadIdx.x & 63, r = lane & 15, lg = lane >> 4;
    for (int k0 = 0; k0 < K; k0 += 32) {
        int kk = k0 + lg * 8;
        const u16* Ab; int ka, lda;
        if (k0 < asplit) { Ab = A0; ka = kk; lda = lda0; }
        else             { Ab = A1; ka = kk - asplit; lda = lda1; }
        bf16x8 a0 = *(const bf16x8*)(Ab + (size_t)(m_base + r) * lda + ka);
        bf16x8 a1 = *(const bf16x8*)(Ab + (size_t)(m_base + 16 + r) * lda + ka);
#pragma unroll
        for (int j = 0; j < 4; ++j) {
            if (j < nt) {
                bf16x8 wf = *(const bf16x8*)(W + (size_t)(n_base + j * 16 + r) * ldw + kk);
                acc[0][j] = MFMA16(a0, wf, acc[0][j]);
                acc[1][j] = MFMA16(a1, wf, acc[1][j]);
            }
        }
    }
}

// ---------------- one-time conversion / packing kernels ----------------

__global__ __launch_bounds__(256) void k_cvt8(
    const float* __restrict__ s0, const float* __restrict__ s1, const float* __restrict__ s2,
    const float* __restrict__ s3, const float* __restrict__ s4, const float* __restrict__ s5,
    const float* __restrict__ s6, const float* __restrict__ s7,
    u16* __restrict__ d0, u16* __restrict__ d1, u16* __restrict__ d2, u16* __restrict__ d3,
    u16* __restrict__ d4, u16* __restrict__ d5, u16* __restrict__ d6, u16* __restrict__ d7) {
    int i = blockIdx.x * 256 + threadIdx.x;
    const int S = 262144;
    if (i < 6 * S) {
        int seg = i >> 18, off = i & (S - 1);
        const float* s = seg == 0 ? s0 : seg == 1 ? s1 : seg == 2 ? s2 : seg == 3 ? s3 : seg == 4 ? s4 : s5;
        u16* d = seg == 0 ? d0 : seg == 1 ? d1 : seg == 2 ? d2 : seg == 3 ? d3 : seg == 4 ? d4 : d5;
        d[off] = f2bf(s[off]);
    } else if (i < 6 * S + 5120000) {
        int off = i - 6 * S;
        d6[off] = f2bf(s6[off]);
    } else {
        int off = i - 6 * S - 5120000;
        if (off < 3211264) d7[off] = f2bf(s7[off]);
    }
}

__global__ __launch_bounds__(256) void k_packX(const float* __restrict__ w_ih1,
                                               const float* __restrict__ s_wx,
                                               u16* __restrict__ W1X, u16* __restrict__ WSX) {
    int i = blockIdx.x * 256 + threadIdx.x;
    if (i < 2097152) {
        W1X[i] = f2bf(w_ih1[(size_t)(i >> 10) * 1536 + 512 + (i & 1023)]);
    } else if (i < 2621440) {
        int i2 = i - 2097152;
        WSX[i2] = f2bf(s_wx[(size_t)(i2 >> 10) * 1536 + 512 + (i2 & 1023)]);
    }
}

// Col-parallel scan weight layouts (colg = owning block's slice):
//  W1S [2560][1024]: row' = colg*160 + g*32 + dl (g in {i,f,g,o,sent}), d = colg*32+dl
//  W2H [2048][1024]: row' = colg*128 + g*32 + dl; K = [h1n | h2]
//  W2A [2048][ 512]: row' = colg*128 + g*32 + dl; K = att
__global__ __launch_bounds__(256) void k_packS(
    const float* __restrict__ w_ih1, const float* __restrict__ w_hh1,
    const float* __restrict__ s_wx, const float* __restrict__ s_wh,
    const float* __restrict__ w_ih2, const float* __restrict__ w_hh2,
    u16* __restrict__ W1S, u16* __restrict__ W2H, u16* __restrict__ W2A) {
    int i = blockIdx.x * 256 + threadIdx.x;
    if (i < 2621440) {
        int rp = i >> 10, k = i & 1023;
        int colg = rp / 160, rem = rp - colg * 160, g = rem >> 5, dl = rem & 31;
        int d = colg * 32 + dl;
        float v;
        if (g < 4) v = (k < 512) ? w_ih1[(size_t)(g * 512 + d) * 1536 + k]
                                 : w_hh1[(size_t)(g * 512 + d) * 512 + (k - 512)];
        else       v = (k < 512) ? s_wx[(size_t)d * 1536 + k]
                                 : s_wh[(size_t)d * 512 + (k - 512)];
        W1S[i] = f2bf(v);
    } else if (i < 2621440 + 2097152) {
        int i2 = i - 2621440;
        int rp = i2 >> 10, k = i2 & 1023;
        int colg = rp >> 7, rem = rp & 127, g = rem >> 5, dl = rem & 31;
        int d = colg * 32 + dl;
        float v = (k < 512) ? w_ih2[(size_t)(g * 512 + d) * 1024 + 512 + k]
                            : w_hh2[(size_t)(g * 512 + d) * 512 + (k - 512)];
        W2H[i2] = f2bf(v);
    } else if (i < 2621440 + 2097152 + 1048576) {
        int i3 = i - 2621440 - 2097152;
        int rp = i3 >> 9, k = i3 & 511;
        int colg = rp >> 7, rem = rp & 127, g = rem >> 5, dl = rem & 31;
        int d = colg * 32 + dl;
        W2A[i3] = f2bf(w_ih2[(size_t)(g * 512 + d) * 1024 + k]);
    }
}

__global__ __launch_bounds__(256) void k_xw(const float* __restrict__ emb, const float* __restrict__ gimg,
                                            const int* __restrict__ cap, u16* __restrict__ XW, int total) {
    int i = blockIdx.x * 256 + threadIdx.x;
    if (i >= total) return;
    int t = i >> 17;
    int rem = i & ((1 << 17) - 1);
    int b = rem >> 10, k = rem & 1023;
    float v = (k < 512) ? emb[(size_t)cap[b * 50 + t] * 512 + k] : gimg[b * 512 + (k - 512)];
    XW[i] = f2bf(v);
}

// ---------------- batched precompute GEMMs ----------------

__global__ __launch_bounds__(256) void k_p1ps(const u16* __restrict__ XW, const u16* __restrict__ W1X,
                                              const u16* __restrict__ WSX,
                                              const float* __restrict__ b_ih1, const float* __restrict__ b_hh1,
                                              const float* __restrict__ s_bx, const float* __restrict__ s_bh,
                                              float* __restrict__ P1, float* __restrict__ PS) {
    int bid = blockIdx.x;
    int ng = bid % 40, mg = bid / 40;
    int w = threadIdx.x >> 6, lane = threadIdx.x & 63, r = lane & 15, lg = lane >> 4;
    int m_base = mg * 128 + w * 32;
    f32x4 acc[2][4] = {};
    if (ng < 32) {
        int n_base = ng * 64;
        gemm_2x4(XW, XW, 1 << 28, 1024, 1024, W1X, 1024, 1024, m_base, n_base, 4, acc);
#pragma unroll
        for (int mt = 0; mt < 2; ++mt)
#pragma unroll
            for (int j = 0; j < 4; ++j)
#pragma unroll
                for (int reg = 0; reg < 4; ++reg) {
                    int row = m_base + mt * 16 + lg * 4 + reg;
                    int col = n_base + j * 16 + r;
                    P1[(size_t)row * 2048 + col] = acc[mt][j][reg] + b_ih1[col] + b_hh1[col];
                }
    } else {
        int n_base = (ng - 32) * 64;
        gemm_2x4(XW, XW, 1 << 28, 1024, 1024, WSX, 1024, 1024, m_base, n_base, 4, acc);
#pragma unroll
        for (int mt = 0; mt < 2; ++mt)
#pragma unroll
            for (int j = 0; j < 4; ++j)
#pragma unroll
                for (int reg = 0; reg < 4; ++reg) {
                    int row = m_base + mt * 16 + lg * 4 + reg;
                    int col = n_base + j * 16 + r;
                    PS[(size_t)row * 512 + col] = acc[mt][j][reg] + s_bx[col] + s_bh[col];
                }
    }
}

__global__ __launch_bounds__(256) void k_va(const u16* __restrict__ SPB, const u16* __restrict__ WVB,
                                            const float* __restrict__ wv_b, u16* __restrict__ VAB) {
    int bid = blockIdx.x;
    int ng = bid % 8, mg = bid / 8;
    int w = threadIdx.x >> 6, lane = threadIdx.x & 63, r = lane & 15, lg = lane >> 4;
    int m_base = mg * 128 + w * 32;
    int n_base = ng * 64;
    f32x4 acc[2][4] = {};
    gemm_2x4(SPB, SPB, 1 << 28, 512, 512, WVB, 512, 512, m_base, n_base, 4, acc);
#pragma unroll
    for (int mt = 0; mt < 2; ++mt)
#pragma unroll
        for (int j = 0; j < 4; ++j)
#pragma unroll
            for (int reg = 0; reg < 4; ++reg) {
                int row = m_base + mt * 16 + lg * 4 + reg;
                int col = n_base + j * 16 + r;
                VAB[(size_t)row * 512 + col] = f2bf(acc[mt][j][reg] + wv_b[col]);
            }
}

// ---------------- persistent scan ----------------

struct AttSm { float whwL[512]; float hidL[2][512]; float zbuf[2][64]; float albuf[2][64]; };

__device__ __forceinline__ void p_attn(int bid, const u16* __restrict__ VAB, const float* SEN,
                                       const float* HID, const float* __restrict__ whw,
                                       const float* __restrict__ whb, const u16* __restrict__ SPB,
                                       const u16* S2, const float* HTF, u16* CHH, AttSm* A) {
    int tid = threadIdx.x;
    int half = tid >> 7, th = tid & 127;
    int b = bid + half * 64;
    for (int i = tid; i < 512; i += 256) A->whwL[i] = whw[i];
    for (int i = th; i < 512; i += 128) A->hidL[half][i] = HID[(size_t)b * 512 + i];
    __syncthreads();
    int w2 = th >> 6, lane = tid & 63;
    for (int p = w2; p < 50; p += 2) {
        float part = 0.f;
        if (p < 49) {
            const u16* src = VAB + ((size_t)b * 49 + p) * 512;
#pragma unroll
            for (int it = 0; it < 8; ++it) {
                int a = lane + it * 64;
                part += tanh_(bf2f(src[a]) + A->hidL[half][a]) * A->whwL[a];
            }
        } else {
#pragma unroll
            for (int it = 0; it < 8; ++it) {
                int a = lane + it * 64;
                part += tanh_(SEN[(size_t)b * 512 + a] + A->hidL[half][a]) * A->whwL[a];
            }
        }
#pragma unroll
        for (int o = 32; o; o >>= 1) part += __shfl_xor(part, o, 64);
        if (lane == 0) A->zbuf[half][p] = part + whb[0];
    }
    __syncthreads();
    if (th < 64) {
        float v = (lane < 50) ? A->zbuf[half][lane] : -1e30f;
        float mx = v;
#pragma unroll
        for (int o = 32; o; o >>= 1) mx = fmaxf(mx, __shfl_xor(mx, o, 64));
        float e = (lane < 50) ? __expf(v - mx) : 0.f;
        float s = e;
#pragma unroll
        for (int o = 32; o; o >>= 1) s += __shfl_xor(s, o, 64);
        if (lane < 50) A->albuf[half][lane] = e / s;
    }
    __syncthreads();
    float a49 = A->albuf[half][49];
    int d0 = th * 4;
    unsigned s2a = *(const unsigned*)(S2 + (size_t)b * 512 + d0);
    unsigned s2b = *(const unsigned*)(S2 + (size_t)b * 512 + d0 + 2);
    float acc0 = a49 * bf2f((u16)s2a), acc1 = a49 * bf2f((u16)(s2a >> 16));
    float acc2 = a49 * bf2f((u16)s2b), acc3 = a49 * bf2f((u16)(s2b >> 16));
    for (int p = 0; p < 49; ++p) {
        const u16* sf = SPB + ((size_t)b * 49 + p) * 512 + d0;
        unsigned q0 = *(const unsigned*)sf, q1 = *(const unsigned*)(sf + 2);
        float al = A->albuf[half][p];
        acc0 += al * bf2f((u16)q0); acc1 += al * bf2f((u16)(q0 >> 16));
        acc2 += al * bf2f((u16)q1); acc3 += al * bf2f((u16)(q1 >> 16));
    }
    acc0 += HTF[(size_t)b * 512 + d0];
    acc1 += HTF[(size_t)b * 512 + d0 + 1];
    acc2 += HTF[(size_t)b * 512 + d0 + 2];
    acc3 += HTF[(size_t)b * 512 + d0 + 3];
    ull pk = (ull)((unsigned)f2bf(acc0) | ((unsigned)f2bf(acc1) << 16))
           | ((ull)((unsigned)f2bf(acc2) | ((unsigned)f2bf(acc3) << 16)) << 32);
    st64u(CHH + (size_t)b * 512 + d0, pk);
    __syncthreads();
}

__global__ __launch_bounds__(256) void k_scan(
    const u16* __restrict__ W1S, const u16* __restrict__ W2H, const u16* __restrict__ W2A,
    const u16* __restrict__ AFFS, const u16* __restrict__ AFFH,
    const u16* __restrict__ WSB, const u16* __restrict__ WGB, const u16* __restrict__ WPB,
    const float* __restrict__ P1, const float* __restrict__ PS,
    const u16* __restrict__ VAB, const u16* __restrict__ SPB,
    const float* __restrict__ b_ih2, const float* __restrict__ b_hh2,
    const float* __restrict__ affs_b, const float* __restrict__ affh_b,
    const float* __restrict__ wg_b, const float* __restrict__ ws_b, const float* __restrict__ wp_b,
    const float* __restrict__ whw, const float* __restrict__ whb,
    u16* H1R, u16* H2R, u16* STR, u16* S2R, u16* CHHR, u16* ATTR,
    float* HTFR, float* SENR, float* HIDR, int* bar) {
    union SmemU {
        u16 stage[65536];   // 128 KB: full-A stage (col) or 64K A + 64K chain-B (row)
        AttSm att;
    };
    __shared__ SmemU sm;
    u16* lds = sm.stage;
    const int bid = blockIdx.x;
    const int tid = threadIdx.x;
    const int w = tid >> 6, lane = tid & 63, r = lane & 15, lg = lane >> 4;

    float m1[16], m2[16];
#pragma unroll
    for (int i = 0; i < 16; ++i) { m1[i] = 0.f; m2[i] = 0.f; }

    int bi = 0;
    for (int t = 0; t < 49; ++t) {
        u16* H2c = H2R + (size_t)t * 65536;
        u16* H2n = H2R + (size_t)(t + 1) * 65536;
        u16* H1c = H1R + (size_t)t * 65536;
        u16* H1n = H1R + (size_t)(t + 1) * 65536;
        u16* STt = STR + (size_t)t * 65536;
        u16* S2t = S2R + (size_t)t * 65536;
        u16* CHHt = CHHR + (size_t)t * 65536;
        u16* ATTt = ATTR + (size_t)t * 65536;
        float* HTFt = HTFR + (size_t)t * 65536;
        float* SENt = SENR + (size_t)t * 65536;
        float* HIDt = HIDR + (size_t)t * 65536;

        // ---- Ph1: LSTM1 + sentinel (blocks 0..15, col-parallel) ----
        if (bid < 16) {
            int colg = bid;
            f32x4 acc[2][10] = {};
            stageR<128>(lds, H2c);
            compF<10>(lds, W1S, 1024, 0, colg * 160, acc);
            stageR<128>(lds, H1c);
            compF<10>(lds, W1S, 1024, 512, colg * 160, acc);
#pragma unroll
            for (int mt = 0; mt < 2; ++mt)
#pragma unroll
                for (int dh = 0; dh < 2; ++dh)
#pragma unroll
                    for (int reg = 0; reg < 4; ++reg) {
                        int row = w * 32 + mt * 16 + lg * 4 + reg;
                        int d = colg * 32 + dh * 16 + r;
                        const float* p1r = P1 + ((size_t)t * 128 + row) * 2048;
                        float gi = acc[mt][0 + dh][reg] + p1r[d];
                        float gf = acc[mt][2 + dh][reg] + p1r[512 + d];
                        float gg = acc[mt][4 + dh][reg] + p1r[1024 + d];
                        float go = acc[mt][6 + dh][reg] + p1r[1536 + d];
                        float gs = acc[mt][8 + dh][reg] + PS[((size_t)t * 128 + row) * 512 + d];
                        int mi = (mt * 2 + dh) * 4 + reg;
                        float m1n = sigm(gf) * m1[mi] + sigm(gi) * tanh_(gg);
                        m1[mi] = m1n;
                        float tm = tanh_(m1n);
                        st16(H1n + row * 512 + d, f2bf(sigm(go) * tm));
                        st16(STt + row * 512 + d, f2bf(sigm(gs) * tm));
                    }
        }
        grid_barrier(bar, bi++);

        // ---- Ph2: g2p (16..31, col) ; s2->sen chain (32..33) ; ht->hid chain (34..35) ----
        f32x4 g2acc[2][8] = {};
        if (bid >= 16 && bid < 32) {
            int colg = bid - 16;
            stageR<128>(lds, H1n);
            compF<8>(lds, W2H, 1024, 0, colg * 128, g2acc);
            stageR<128>(lds, H2c);
            compF<8>(lds, W2H, 1024, 512, colg * 128, g2acc);
        } else if (bid >= 32 && bid < 34) {
            chain64<0>((bid - 32) * 64, STt, AFFS, affs_b, WSB, ws_b, S2t, (float*)0, SENt, lds);
        } else if (bid >= 34 && bid < 36) {
            chain64<1>((bid - 34) * 64, H1n, AFFH, affh_b, WGB, wg_b, (u16*)0, HTFt, HIDt, lds);
        }
        grid_barrier(bar, bi++);

        // ---- Ph3: attention (all 64 blocks, 2 batch rows each) ----
        p_attn(bid, VAB, SENt, HIDt, whw, whb, SPB, S2t, HTFt, CHHt, &sm.att);
        grid_barrier(bar, bi++);

        // ---- Ph4: att = tanh(chh @ wp^T + b) (blocks 32..33, row chain) ----
        if (bid >= 32 && bid < 34) {
            chain64<2>((bid - 32) * 64, CHHt, WPB, wp_b, (const u16*)0, (const float*)0,
                       ATTt, (float*)0, (float*)0, lds);
        }
        grid_barrier(bar, bi++);

        // ---- Ph5: LSTM2 (blocks 16..31, col; consumes register-parked g2acc) ----
        if (bid >= 16 && bid < 32) {
            int colg = bid - 16;
            stageR<128>(lds, ATTt);
            compF<8>(lds, W2A, 512, 0, colg * 128, g2acc);
#pragma unroll
            for (int mt = 0; mt < 2; ++mt)
#pragma unroll
                for (int dh = 0; dh < 2; ++dh)
#pragma unroll
                    for (int reg = 0; reg < 4; ++reg) {
                        int row = w * 32 + mt * 16 + lg * 4 + reg;
                        int d = colg * 32 + dh * 16 + r;
                        float gi = g2acc[mt][0 + dh][reg] + b_ih2[d]        + b_hh2[d];
                        float gf = g2acc[mt][2 + dh][reg] + b_ih2[512 + d]  + b_hh2[512 + d];
                        float gg = g2acc[mt][4 + dh][reg] + b_ih2[1024 + d] + b_hh2[1024 + d];
                        float go = g2acc[mt][6 + dh][reg] + b_ih2[1536 + d] + b_hh2[1536 + d];
                        int mi = (mt * 2 + dh) * 4 + reg;
                        float m2n = sigm(gf) * m2[mi] + sigm(gi) * tanh_(gg);
                        m2[mi] = m2n;
                        st16(H2n + row * 512 + d, f2bf(sigm(go) * tanh_(m2n)));
                    }
        }
        if (t < 48) grid_barrier(bar, bi++);
    }
}

// Final: preds[b][t][v] = H2R[(t+1)*128+b] @ fc_w^T + fc_b
__global__ __launch_bounds__(256) void k_fc(const u16* __restrict__ H2, const u16* __restrict__ FCB,
                                            const float* __restrict__ fc_b, float* __restrict__ out) {
    int bid = blockIdx.x;
    int ng = bid % 157, mg = bid / 157;
    int w = threadIdx.x >> 6, lane = threadIdx.x & 63, r = lane & 15, lg = lane >> 4;
    int m_base = mg * 128 + w * 32;
    int n_base = ng * 64;
    int nt = (10000 - n_base) / 16; if (nt > 4) nt = 4;
    f32x4 acc[2][4] = {};
    gemm_2x4(H2, H2, 1 << 28, 512, 512, FCB, 512, 512, m_base, n_base, nt, acc);
#pragma unroll
    for (int mt = 0; mt < 2; ++mt)
#pragma unroll
        for (int j = 0; j < 4; ++j) {
            if (j < nt) {
#pragma unroll
                for (int reg = 0; reg < 4; ++reg) {
                    int row = m_base + mt * 16 + lg * 4 + reg;
                    int col = n_base + j * 16 + r;
                    int t = row >> 7, b = row & 127;
                    out[((size_t)b * 49 + t) * 10000 + col] = acc[mt][j][reg] + fc_b[col];
                }
            }
        }
}

// ---------------------------------------------------------------------------

extern "C" void kernel_launch(void* const* d_in, const int* in_sizes, int n_in,
                              void* d_out, int out_size, void* d_ws, size_t ws_size,
                              hipStream_t stream) {
    (void)in_sizes; (void)n_in; (void)out_size; (void)ws_size;

    const float* SF      = (const float*)d_in[0];
    const float* GIMG    = (const float*)d_in[1];
    const int*   CAP     = (const int*)d_in[2];
    const float* EMB     = (const float*)d_in[4];
    const float* w_ih1   = (const float*)d_in[5];
    const float* w_hh1   = (const float*)d_in[6];
    const float* b_ih1   = (const float*)d_in[7];
    const float* b_hh1   = (const float*)d_in[8];
    const float* s_wx    = (const float*)d_in[9];
    const float* s_bx    = (const float*)d_in[10];
    const float* s_wh    = (const float*)d_in[11];
    const float* s_bh    = (const float*)d_in[12];
    const float* w_ih2   = (const float*)d_in[13];
    const float* w_hh2   = (const float*)d_in[14];
    const float* b_ih2   = (const float*)d_in[15];
    const float* b_hh2   = (const float*)d_in[16];
    const float* aff_s_w = (const float*)d_in[17];
    const float* aff_s_b = (const float*)d_in[18];
    const float* aff_h_w = (const float*)d_in[19];
    const float* aff_h_b = (const float*)d_in[20];
    const float* ws_w    = (const float*)d_in[21];
    const float* ws_b    = (const float*)d_in[22];
    const float* wg_w    = (const float*)d_in[23];
    const float* wg_b    = (const float*)d_in[24];
    const float* wv_w    = (const float*)d_in[25];
    const float* wv_b    = (const float*)d_in[26];
    const float* wh_w    = (const float*)d_in[27];
    const float* wh_b    = (const float*)d_in[28];
    const float* wp_w    = (const float*)d_in[29];
    const float* wp_b    = (const float*)d_in[30];
    const float* fc_w    = (const float*)d_in[31];
    const float* fc_b    = (const float*)d_in[32];

    float* out = (float*)d_out;

    // fp32 scratch in d_out (fc overwrites all of d_out at the end):
    float* P1 = out;                       // 49*128*2048 floats
    float* PS = out + 12845056;            //  3,211,264 floats
    u16*  XWB = (u16*)(out + 17000000);    //  6,422,528 u16 (consumed before scan)
    // rotating per-step buffers (scan-only; fc overwrites later):
    u16*   H1R  = (u16*)(out + 21000000);  // 50*65536 u16
    u16*   STR  = (u16*)(out + 22700000);  // 49*65536 u16
    u16*   S2R  = (u16*)(out + 24400000);
    u16*   CHHR = (u16*)(out + 26100000);
    u16*   ATTR = (u16*)(out + 27800000);
    float* HTFR = out + 29500000;          // 49*65536 f32
    float* SENR = out + 32800000;
    float* HIDR = out + 36100000;          // ends ~39.3M < 62.72M

    char* ws = (char*)d_ws;
    size_t off = 0;
    auto alloc = [&](size_t elts, size_t esz) -> void* {
        void* p = ws + off;
        off += (elts * esz + 255) & ~(size_t)255;
        return p;
    };
    u16* W1S   = (u16*)alloc(2621440, 2);
    u16* W2H   = (u16*)alloc(2097152, 2);
    u16* W2A   = (u16*)alloc(1048576, 2);
    u16* W1X   = (u16*)alloc(2097152, 2);
    u16* WSX   = (u16*)alloc(524288, 2);
    u16* AFFS  = (u16*)alloc(262144, 2);
    u16* AFFH  = (u16*)alloc(262144, 2);
    u16* WSB   = (u16*)alloc(262144, 2);
    u16* WGB   = (u16*)alloc(262144, 2);
    u16* WVB   = (u16*)alloc(262144, 2);
    u16* WPB   = (u16*)alloc(262144, 2);
    u16* FCB   = (u16*)alloc(5120000, 2);
    u16* SPB   = (u16*)alloc(3211264, 2);
    u16* VAB   = (u16*)alloc(3211264, 2);
    u16* H2R   = (u16*)alloc(3276800, 2);  // 50*65536 u16 (read by k_fc)
    int* BAR   = (int*)alloc(2048, 4);

    // zero-init step-0 state + barrier counters (every call / replay)
    hipMemsetAsync(H1R, 0, 65536 * 2, stream);
    hipMemsetAsync(H2R, 0, 65536 * 2, stream);
    hipMemsetAsync(BAR, 0, 2048 * 4, stream);

    // prep: conversions + packs + xw gather
    k_cvt8<<<38688, 256, 0, stream>>>(aff_s_w, aff_h_w, ws_w, wg_w, wv_w, wp_w, fc_w, SF,
                                      AFFS, AFFH, WSB, WGB, WVB, WPB, FCB, SPB);
    k_packX<<<(2621440 + 255) / 256, 256, 0, stream>>>(w_ih1, s_wx, W1X, WSX);
    k_packS<<<(5767168 + 255) / 256, 256, 0, stream>>>(w_ih1, w_hh1, s_wx, s_wh, w_ih2, w_hh2,
                                                       W1S, W2H, W2A);
    k_xw<<<(6422528 + 255) / 256, 256, 0, stream>>>(EMB, GIMG, CAP, XWB, 6422528);

    // batched precompute GEMMs
    k_p1ps<<<49 * 40, 256, 0, stream>>>(XWB, W1X, WSX, b_ih1, b_hh1, s_bx, s_bh, P1, PS);
    k_va<<<49 * 8, 256, 0, stream>>>(SPB, WVB, wv_b, VAB);

    // persistent sequential scan (64 co-resident blocks, fence-free barriers)
    k_scan<<<NBLK, 256, 0, stream>>>(W1S, W2H, W2A, AFFS, AFFH, WSB, WGB, WPB,
                                     P1, PS, VAB, SPB, b_ih2, b_hh2, aff_s_b, aff_h_b,
                                     wg_b, ws_b, wp_b, wh_w, wh_b,
                                     H1R, H2R, STR, S2R, CHHR, ATTR,
                                     HTFR, SENR, HIDR, BAR);

    // final projection to vocab
    k_fc<<<49 * 157, 256, 0, stream>>>(H2R + 65536, FCB, fc_b, out);
}

// Round 8
// 45325.140 us; speedup vs baseline: 1.0238x; 1.0238x over previous
//
#include <hip/hip_runtime.h>

// ---------------------------------------------------------------------------
// Adaptive-attention LSTM decoder (B=128, P=49, D=E=A=512, V=10000, T=50).
//  * Persistent scan: 64 co-resident blocks, 5 phases/step, fence-free grid
//    barriers (atomic counter + vmcnt(0) drain).
//  * ALL scan stores are coalesced 16B/lane write-through (dwordx4 sc0 sc1)
//    via LDS repack -> no partial-sector RMW (the R3-R7 bottleneck).
//  * Col-block outputs in blocked layout [slice16][128][32]; chain/attn
//    outputs in [row][512]. Rotating buffers -> readers use normal cached
//    loads (fresh addresses can't be stale).
//  * Deep staging: full A staged via global_load_lds (aux=0), one drain.
//  * R=1 weight ownership; m1/m2 cell states and g2p partials in registers.
// ---------------------------------------------------------------------------

typedef unsigned short u16;
typedef unsigned long long ull;
typedef short bf16x8 __attribute__((ext_vector_type(8)));
typedef float f32x4 __attribute__((ext_vector_type(4)));
typedef int i32x4 __attribute__((ext_vector_type(4)));

#define MFMA16(a, b, c) __builtin_amdgcn_mfma_f32_16x16x32_bf16(a, b, c, 0, 0, 0)
#define NBLK 64

__device__ __forceinline__ u16 f2bf(float f) {
    union { float f; unsigned u; } v; v.f = f;
    return (u16)((v.u + 0x7fffu + ((v.u >> 16) & 1u)) >> 16);
}
__device__ __forceinline__ float bf2f(u16 h) {
    union { unsigned u; float f; } v; v.u = ((unsigned)h) << 16; return v.f;
}
__device__ __forceinline__ float sigm(float x) {
    x = fminf(fmaxf(x, -30.f), 30.f);
    return 1.f / (1.f + __expf(-x));
}
__device__ __forceinline__ float tanh_(float x) {
    x = fminf(fmaxf(x, -15.f), 15.f);
    float e = __expf(2.f * x);
    return (e - 1.f) / (e + 1.f);
}

// ---- coalesced write-through stores (reach LLC); drained at barrier ----
__device__ __forceinline__ void st16x(void* p, i32x4 v) {
    asm volatile("global_store_dwordx4 %0, %1, off sc0 sc1" :: "v"(p), "v"(v) : "memory");
}
__device__ __forceinline__ void st64u(u16* p, ull v) {
    asm volatile("global_store_dwordx2 %0, %1, off sc0 sc1" :: "v"(p), "v"(v) : "memory");
}

// Fence-free grid barrier: drain own write-through stores, count arrivals.
__device__ __forceinline__ void grid_barrier(int* bar, int idx) {
    asm volatile("s_waitcnt vmcnt(0)" ::: "memory");
    __syncthreads();
    if (threadIdx.x == 0) {
        __hip_atomic_fetch_add(&bar[idx], 1, __ATOMIC_RELAXED, __HIP_MEMORY_SCOPE_AGENT);
        while (__hip_atomic_load(&bar[idx], __ATOMIC_RELAXED, __HIP_MEMORY_SCOPE_AGENT) < NBLK)
            __builtin_amdgcn_s_sleep(1);
    }
    __syncthreads();
    asm volatile("" ::: "memory");
}

// ---------------------------------------------------------------------------
// Deep LDS staging, source-XOR swizzled, aux=0 (cached loads).
// stageL: linear [row][512] source. stageB: blocked [16][128][32] source.
template<int ROWS>
__device__ __forceinline__ void stageL(u16* lds, const u16* __restrict__ A) {
    const int tid = threadIdx.x;
    const int w = tid >> 6, lane = tid & 63;
    constexpr int RPW = ROWS / 4;
    __syncthreads();
#pragma unroll
    for (int i = 0; i < RPW; ++i) {
        int row = w * RPW + i;
        const u16* src = A + (size_t)row * 512 + ((lane ^ (row & 7)) << 3);
        u16* dst = lds + row * 512;
        __builtin_amdgcn_global_load_lds(
            (const __attribute__((address_space(1))) void*)src,
            (__attribute__((address_space(3))) void*)dst, 16, 0, 0);
    }
    asm volatile("s_waitcnt vmcnt(0)" ::: "memory");
    __syncthreads();
}

template<int ROWS>
__device__ __forceinline__ void stageB(u16* lds, const u16* __restrict__ A, int r0) {
    const int tid = threadIdx.x;
    const int w = tid >> 6, lane = tid & 63;
    constexpr int RPW = ROWS / 4;
    __syncthreads();
#pragma unroll
    for (int i = 0; i < RPW; ++i) {
        int row = w * RPW + i;
        int g = lane ^ (row & 7);   // 16B chunk index 0..63 of the 512-col row
        const u16* src = A + (size_t)(g >> 2) * 4096 + (size_t)(r0 + row) * 32 + ((g & 3) << 3);
        u16* dst = lds + row * 512;
        __builtin_amdgcn_global_load_lds(
            (const __attribute__((address_space(1))) void*)src,
            (__attribute__((address_space(3))) void*)dst, 16, 0, 0);
    }
    asm volatile("s_waitcnt vmcnt(0)" ::: "memory");
    __syncthreads();
}

__device__ __forceinline__ bf16x8 ldsF(const u16* lds, int row, int kk) {
    int c16 = kk >> 3;
    return *(const bf16x8*)(lds + row * 512 + ((c16 ^ (row & 7)) << 3));
}

// Col-parallel compute over staged 128x512 A: 4 waves x 32 rows, NT n-tiles.
template<int NT>
__device__ __forceinline__ void compF(const u16* lds, const u16* __restrict__ W,
                                      int ldw, int koff, int wrow0, f32x4 acc[2][NT]) {
    const int tid = threadIdx.x;
    const int lane = tid & 63, r = lane & 15, lg = lane >> 4;
    const int m_base = (tid >> 6) * 32;
    for (int k0 = 0; k0 < 512; k0 += 32) {
        int kk = k0 + lg * 8;
        bf16x8 a0 = ldsF(lds, m_base + r, kk);
        bf16x8 a1 = ldsF(lds, m_base + 16 + r, kk);
#pragma unroll
        for (int j = 0; j < NT; ++j) {
            bf16x8 wf = *(const bf16x8*)(W + (size_t)(wrow0 + j * 16 + r) * ldw + koff + kk);
            acc[0][j] = MFMA16(a0, wf, acc[0][j]);
            acc[1][j] = MFMA16(a1, wf, acc[1][j]);
        }
    }
}

// Row-parallel fused chain on 64 rows [r0, r0+64):
//  V=0: s2 = relu(A@W1^T+b1) -> OBmid bf16 ; sen = s2@W2^T+b2 -> O2 f32
//  V=1: ht = tanh(A@W1^T+b1) -> OBmid bf16 ; hid = ht@W2^T+b2 -> O2 f32
//  V=2: att = tanh(A@W1^T+b1) -> OBmid bf16 (no GEMM2; SRC is linear layout)
template<int V>
__device__ __forceinline__ void chain64(int r0, const u16* SRC,
        const u16* __restrict__ W1, const float* __restrict__ b1,
        const u16* __restrict__ W2, const float* __restrict__ b2,
        u16* OBmid, float* O2, u16* lds) {
    u16* ldsB = lds + 32768;
    const int tid = threadIdx.x;
    const int w = tid >> 6, lane = tid & 63, r = lane & 15, lg = lane >> 4;
    if (V == 2) stageL<64>(lds, SRC + (size_t)r0 * 512);
    else        stageB<64>(lds, SRC, r0);
#pragma unroll
    for (int half = 0; half < 2; ++half) {
        f32x4 acc[16] = {};
        for (int k0 = 0; k0 < 512; k0 += 32) {
            int kk = k0 + lg * 8;
            bf16x8 a = ldsF(lds, w * 16 + r, kk);
#pragma unroll
            for (int j = 0; j < 16; ++j) {
                bf16x8 wf = *(const bf16x8*)(W1 + (size_t)(half * 256 + j * 16 + r) * 512 + kk);
                acc[j] = MFMA16(a, wf, acc[j]);
            }
        }
#pragma unroll
        for (int j = 0; j < 16; ++j)
#pragma unroll
            for (int reg = 0; reg < 4; ++reg) {
                int lrow = w * 16 + lg * 4 + reg;
                int col = half * 256 + j * 16 + r;
                float v = acc[j][reg] + b1[col];
                v = (V == 0) ? fmaxf(v, 0.f) : tanh_(v);
                ldsB[lrow * 512 + (((col >> 3) ^ (lrow & 7)) << 3) + (col & 7)] = f2bf(v);
            }
    }
    __syncthreads();
    // flush ldsB -> OBmid ([row][512] bf16), fully coalesced 16B stores
#pragma unroll
    for (int i = 0; i < 16; ++i) {
        int q = i * 256 + tid;
        int lrow = q >> 6, c16 = q & 63;
        i32x4 v = *(const i32x4*)(ldsB + ((lrow * 64 + (c16 ^ (lrow & 7))) << 3));
        st16x(OBmid + ((size_t)(r0 + lrow) * 512 + (c16 << 3)), v);
    }
    if (V == 2) return;
    __syncthreads();
    float* F32L = (float*)lds;   // stage region dead after GEMM1
#pragma unroll
    for (int half = 0; half < 2; ++half) {
        f32x4 acc[16] = {};
        for (int k0 = 0; k0 < 512; k0 += 32) {
            int kk = k0 + lg * 8;
            bf16x8 a = ldsF(ldsB, w * 16 + r, kk);
#pragma unroll
            for (int j = 0; j < 16; ++j) {
                bf16x8 wf = *(const bf16x8*)(W2 + (size_t)(half * 256 + j * 16 + r) * 512 + kk);
                acc[j] = MFMA16(a, wf, acc[j]);
            }
        }
#pragma unroll
        for (int j = 0; j < 16; ++j)
#pragma unroll
            for (int reg = 0; reg < 4; ++reg) {
                int lrow = w * 16 + lg * 4 + reg;
                int colL = j * 16 + r;
                F32L[lrow * 256 + colL] = acc[j][reg] + b2[half * 256 + colL];
            }
        __syncthreads();
#pragma unroll
        for (int i = 0; i < 16; ++i) {
            int q = i * 256 + tid;
            int lrow = q >> 6, c = q & 63;
            i32x4 v = *(const i32x4*)(F32L + lrow * 256 + c * 4);
            st16x(O2 + (size_t)(r0 + lrow) * 512 + half * 256 + c * 4, v);
        }
        __syncthreads();
    }
}

// Plain-global-A gemm (pre/post kernels only).
__device__ __forceinline__ void gemm_2x4(const u16* __restrict__ A0, const u16* __restrict__ A1,
                                         int asplit, int lda0, int lda1,
                                         const u16* __restrict__ W, int ldw, int K,
                                         int m_base, int n_base, int nt, f32x4 acc[2][4]) {
    const int lane = threadIdx.x & 63, r = lane & 15, lg = lane >> 4;
    for (int k0 = 0; k0 < K; k0 += 32) {
        int kk = k0 + lg * 8;
        const u16* Ab; int ka, lda;
        if (k0 < asplit) { Ab = A0; ka = kk; lda = lda0; }
        else             { Ab = A1; ka = kk - asplit; lda = lda1; }
        bf16x8 a0 = *(const bf16x8*)(Ab + (size_t)(m_base + r) * lda + ka);
        bf16x8 a1 = *(const bf16x8*)(Ab + (size_t)(m_base + 16 + r) * lda + ka);
#pragma unroll
        for (int j = 0; j < 4; ++j) {
            if (j < nt) {
                bf16x8 wf = *(const bf16x8*)(W + (size_t)(n_base + j * 16 + r) * ldw + kk);
                acc[0][j] = MFMA16(a0, wf, acc[0][j]);
                acc[1][j] = MFMA16(a1, wf, acc[1][j]);
            }
        }
    }
}

// ---------------- one-time conversion / packing kernels ----------------

__global__ __launch_bounds__(256) void k_cvt8(
    const float* __restrict__ s0, const float* __restrict__ s1, const float* __restrict__ s2,
    const float* __restrict__ s3, const float* __restrict__ s4, const float* __restrict__ s5,
    const float* __restrict__ s6, const float* __restrict__ s7,
    u16* __restrict__ d0, u16* __restrict__ d1, u16* __restrict__ d2, u16* __restrict__ d3,
    u16* __restrict__ d4, u16* __restrict__ d5, u16* __restrict__ d6, u16* __restrict__ d7) {
    int i = blockIdx.x * 256 + threadIdx.x;
    const int S = 262144;
    if (i < 6 * S) {
        int seg = i >> 18, off = i & (S - 1);
        const float* s = seg == 0 ? s0 : seg == 1 ? s1 : seg == 2 ? s2 : seg == 3 ? s3 : seg == 4 ? s4 : s5;
        u16* d = seg == 0 ? d0 : seg == 1 ? d1 : seg == 2 ? d2 : seg == 3 ? d3 : seg == 4 ? d4 : d5;
        d[off] = f2bf(s[off]);
    } else if (i < 6 * S + 5120000) {
        int off = i - 6 * S;
        d6[off] = f2bf(s6[off]);
    } else {
        int off = i - 6 * S - 5120000;
        if (off < 3211264) d7[off] = f2bf(s7[off]);
    }
}

__global__ __launch_bounds__(256) void k_packX(const float* __restrict__ w_ih1,
                                               const float* __restrict__ s_wx,
                                               u16* __restrict__ W1X, u16* __restrict__ WSX) {
    int i = blockIdx.x * 256 + threadIdx.x;
    if (i < 2097152) {
        W1X[i] = f2bf(w_ih1[(size_t)(i >> 10) * 1536 + 512 + (i & 1023)]);
    } else if (i < 2621440) {
        int i2 = i - 2097152;
        WSX[i2] = f2bf(s_wx[(size_t)(i2 >> 10) * 1536 + 512 + (i2 & 1023)]);
    }
}

// Col-parallel scan weight layouts (colg = owning block's slice):
//  W1S [2560][1024]: row' = colg*160 + g*32 + dl (g in {i,f,g,o,sent}), d = colg*32+dl
//  W2H [2048][1024]: row' = colg*128 + g*32 + dl; K = [h1n | h2]
//  W2A [2048][ 512]: row' = colg*128 + g*32 + dl; K = att
__global__ __launch_bounds__(256) void k_packS(
    const float* __restrict__ w_ih1, const float* __restrict__ w_hh1,
    const float* __restrict__ s_wx, const float* __restrict__ s_wh,
    const float* __restrict__ w_ih2, const float* __restrict__ w_hh2,
    u16* __restrict__ W1S, u16* __restrict__ W2H, u16* __restrict__ W2A) {
    int i = blockIdx.x * 256 + threadIdx.x;
    if (i < 2621440) {
        int rp = i >> 10, k = i & 1023;
        int colg = rp / 160, rem = rp - colg * 160, g = rem >> 5, dl = rem & 31;
        int d = colg * 32 + dl;
        float v;
        if (g < 4) v = (k < 512) ? w_ih1[(size_t)(g * 512 + d) * 1536 + k]
                                 : w_hh1[(size_t)(g * 512 + d) * 512 + (k - 512)];
        else       v = (k < 512) ? s_wx[(size_t)d * 1536 + k]
                                 : s_wh[(size_t)d * 512 + (k - 512)];
        W1S[i] = f2bf(v);
    } else if (i < 2621440 + 2097152) {
        int i2 = i - 2621440;
        int rp = i2 >> 10, k = i2 & 1023;
        int colg = rp >> 7, rem = rp & 127, g = rem >> 5, dl = rem & 31;
        int d = colg * 32 + dl;
        float v = (k < 512) ? w_ih2[(size_t)(g * 512 + d) * 1024 + 512 + k]
                            : w_hh2[(size_t)(g * 512 + d) * 512 + (k - 512)];
        W2H[i2] = f2bf(v);
    } else if (i < 2621440 + 2097152 + 1048576) {
        int i3 = i - 2621440 - 2097152;
        int rp = i3 >> 9, k = i3 & 511;
        int colg = rp >> 7, rem = rp & 127, g = rem >> 5, dl = rem & 31;
        int d = colg * 32 + dl;
        W2A[i3] = f2bf(w_ih2[(size_t)(g * 512 + d) * 1024 + k]);
    }
}

__global__ __launch_bounds__(256) void k_xw(const float* __restrict__ emb, const float* __restrict__ gimg,
                                            const int* __restrict__ cap, u16* __restrict__ XW, int total) {
    int i = blockIdx.x * 256 + threadIdx.x;
    if (i >= total) return;
    int t = i >> 17;
    int rem = i & ((1 << 17) - 1);
    int b = rem >> 10, k = rem & 1023;
    float v = (k < 512) ? emb[(size_t)cap[b * 50 + t] * 512 + k] : gimg[b * 512 + (k - 512)];
    XW[i] = f2bf(v);
}

// ---------------- batched precompute GEMMs ----------------

__global__ __launch_bounds__(256) void k_p1ps(const u16* __restrict__ XW, const u16* __restrict__ W1X,
                                              const u16* __restrict__ WSX,
                                              const float* __restrict__ b_ih1, const float* __restrict__ b_hh1,
                                              const float* __restrict__ s_bx, const float* __restrict__ s_bh,
                                              float* __restrict__ P1, float* __restrict__ PS) {
    int bid = blockIdx.x;
    int ng = bid % 40, mg = bid / 40;
    int w = threadIdx.x >> 6, lane = threadIdx.x & 63, r = lane & 15, lg = lane >> 4;
    int m_base = mg * 128 + w * 32;
    f32x4 acc[2][4] = {};
    if (ng < 32) {
        int n_base = ng * 64;
        gemm_2x4(XW, XW, 1 << 28, 1024, 1024, W1X, 1024, 1024, m_base, n_base, 4, acc);
#pragma unroll
        for (int mt = 0; mt < 2; ++mt)
#pragma unroll
            for (int j = 0; j < 4; ++j)
#pragma unroll
                for (int reg = 0; reg < 4; ++reg) {
                    int row = m_base + mt * 16 + lg * 4 + reg;
                    int col = n_base + j * 16 + r;
                    P1[(size_t)row * 2048 + col] = acc[mt][j][reg] + b_ih1[col] + b_hh1[col];
                }
    } else {
        int n_base = (ng - 32) * 64;
        gemm_2x4(XW, XW, 1 << 28, 1024, 1024, WSX, 1024, 1024, m_base, n_base, 4, acc);
#pragma unroll
        for (int mt = 0; mt < 2; ++mt)
#pragma unroll
            for (int j = 0; j < 4; ++j)
#pragma unroll
                for (int reg = 0; reg < 4; ++reg) {
                    int row = m_base + mt * 16 + lg * 4 + reg;
                    int col = n_base + j * 16 + r;
                    PS[(size_t)row * 512 + col] = acc[mt][j][reg] + s_bx[col] + s_bh[col];
                }
    }
}

__global__ __launch_bounds__(256) void k_va(const u16* __restrict__ SPB, const u16* __restrict__ WVB,
                                            const float* __restrict__ wv_b, u16* __restrict__ VAB) {
    int bid = blockIdx.x;
    int ng = bid % 8, mg = bid / 8;
    int w = threadIdx.x >> 6, lane = threadIdx.x & 63, r = lane & 15, lg = lane >> 4;
    int m_base = mg * 128 + w * 32;
    int n_base = ng * 64;
    f32x4 acc[2][4] = {};
    gemm_2x4(SPB, SPB, 1 << 28, 512, 512, WVB, 512, 512, m_base, n_base, 4, acc);
#pragma unroll
    for (int mt = 0; mt < 2; ++mt)
#pragma unroll
        for (int j = 0; j < 4; ++j)
#pragma unroll
            for (int reg = 0; reg < 4; ++reg) {
                int row = m_base + mt * 16 + lg * 4 + reg;
                int col = n_base + j * 16 + r;
                VAB[(size_t)row * 512 + col] = f2bf(acc[mt][j][reg] + wv_b[col]);
            }
}

// ---------------- persistent scan ----------------

struct AttSm { float whwL[512]; float hidL[2][512]; float zbuf[2][64]; float albuf[2][64]; };

__device__ __forceinline__ void p_attn(int bid, const u16* __restrict__ VAB, const float* SEN,
                                       const float* HID, const float* __restrict__ whw,
                                       const float* __restrict__ whb, const u16* __restrict__ SPB,
                                       const u16* S2, const u16* HTB, u16* CHH, AttSm* A) {
    int tid = threadIdx.x;
    int half = tid >> 7, th = tid & 127;
    int b = bid + half * 64;
    for (int i = tid; i < 512; i += 256) A->whwL[i] = whw[i];
    for (int i = th; i < 512; i += 128) A->hidL[half][i] = HID[(size_t)b * 512 + i];
    __syncthreads();
    int w2 = th >> 6, lane = tid & 63;
    for (int p = w2; p < 50; p += 2) {
        float part = 0.f;
        if (p < 49) {
            const u16* src = VAB + ((size_t)b * 49 + p) * 512;
#pragma unroll
            for (int it = 0; it < 8; ++it) {
                int a = lane + it * 64;
                part += tanh_(bf2f(src[a]) + A->hidL[half][a]) * A->whwL[a];
            }
        } else {
#pragma unroll
            for (int it = 0; it < 8; ++it) {
                int a = lane + it * 64;
                part += tanh_(SEN[(size_t)b * 512 + a] + A->hidL[half][a]) * A->whwL[a];
            }
        }
#pragma unroll
        for (int o = 32; o; o >>= 1) part += __shfl_xor(part, o, 64);
        if (lane == 0) A->zbuf[half][p] = part + whb[0];
    }
    __syncthreads();
    if (th < 64) {
        float v = (lane < 50) ? A->zbuf[half][lane] : -1e30f;
        float mx = v;
#pragma unroll
        for (int o = 32; o; o >>= 1) mx = fmaxf(mx, __shfl_xor(mx, o, 64));
        float e = (lane < 50) ? __expf(v - mx) : 0.f;
        float s = e;
#pragma unroll
        for (int o = 32; o; o >>= 1) s += __shfl_xor(s, o, 64);
        if (lane < 50) A->albuf[half][lane] = e / s;
    }
    __syncthreads();
    float a49 = A->albuf[half][49];
    int d0 = th * 4;
    unsigned s2a = *(const unsigned*)(S2 + (size_t)b * 512 + d0);
    unsigned s2b = *(const unsigned*)(S2 + (size_t)b * 512 + d0 + 2);
    float acc0 = a49 * bf2f((u16)s2a), acc1 = a49 * bf2f((u16)(s2a >> 16));
    float acc2 = a49 * bf2f((u16)s2b), acc3 = a49 * bf2f((u16)(s2b >> 16));
    for (int p = 0; p < 49; ++p) {
        const u16* sf = SPB + ((size_t)b * 49 + p) * 512 + d0;
        unsigned q0 = *(const unsigned*)sf, q1 = *(const unsigned*)(sf + 2);
        float al = A->albuf[half][p];
        acc0 += al * bf2f((u16)q0); acc1 += al * bf2f((u16)(q0 >> 16));
        acc2 += al * bf2f((u16)q1); acc3 += al * bf2f((u16)(q1 >> 16));
    }
    unsigned h01 = *(const unsigned*)(HTB + (size_t)b * 512 + d0);
    unsigned h23 = *(const unsigned*)(HTB + (size_t)b * 512 + d0 + 2);
    acc0 += bf2f((u16)h01); acc1 += bf2f((u16)(h01 >> 16));
    acc2 += bf2f((u16)h23); acc3 += bf2f((u16)(h23 >> 16));
    ull pk = (ull)((unsigned)f2bf(acc0) | ((unsigned)f2bf(acc1) << 16))
           | ((ull)((unsigned)f2bf(acc2) | ((unsigned)f2bf(acc3) << 16)) << 32);
    st64u(CHH + (size_t)b * 512 + d0, pk);
    __syncthreads();
}

__global__ __launch_bounds__(256) void k_scan(
    const u16* __restrict__ W1S, const u16* __restrict__ W2H, const u16* __restrict__ W2A,
    const u16* __restrict__ AFFS, const u16* __restrict__ AFFH,
    const u16* __restrict__ WSB, const u16* __restrict__ WGB, const u16* __restrict__ WPB,
    const float* __restrict__ P1, const float* __restrict__ PS,
    const u16* __restrict__ VAB, const u16* __restrict__ SPB,
    const float* __restrict__ b_ih2, const float* __restrict__ b_hh2,
    const float* __restrict__ affs_b, const float* __restrict__ affh_b,
    const float* __restrict__ wg_b, const float* __restrict__ ws_b, const float* __restrict__ wp_b,
    const float* __restrict__ whw, const float* __restrict__ whb,
    u16* H1R, u16* H2R, u16* STR, u16* S2R, u16* HTBR, u16* CHHR, u16* ATTR,
    float* SENR, float* HIDR, int* bar) {
    union SmemU {
        u16 stage[65536];   // 128 KB
        AttSm att;
    };
    __shared__ SmemU sm;
    u16* lds = sm.stage;
    const int bid = blockIdx.x;
    const int tid = threadIdx.x;
    const int w = tid >> 6, lane = tid & 63, r = lane & 15, lg = lane >> 4;

    float m1[16], m2[16];
#pragma unroll
    for (int i = 0; i < 16; ++i) { m1[i] = 0.f; m2[i] = 0.f; }

    int bi = 0;
    for (int t = 0; t < 49; ++t) {
        u16* H2c = H2R + (size_t)t * 65536;        // blocked [16][128][32]
        u16* H2n = H2R + (size_t)(t + 1) * 65536;
        u16* H1c = H1R + (size_t)t * 65536;        // blocked
        u16* H1n = H1R + (size_t)(t + 1) * 65536;
        u16* STt = STR + (size_t)t * 65536;        // blocked
        u16* S2t = S2R + (size_t)t * 65536;        // [row][512]
        u16* HTBt = HTBR + (size_t)t * 65536;      // [row][512]
        u16* CHHt = CHHR + (size_t)t * 65536;      // [row][512]
        u16* ATTt = ATTR + (size_t)t * 65536;      // [row][512]
        float* SENt = SENR + (size_t)t * 65536;
        float* HIDt = HIDR + (size_t)t * 65536;

        // ---- Ph1: LSTM1 + sentinel (blocks 0..15, col-parallel) ----
        if (bid < 16) {
            int colg = bid;
            f32x4 acc[2][10] = {};
            stageB<128>(lds, H2c, 0);
            compF<10>(lds, W1S, 1024, 0, colg * 160, acc);
            stageB<128>(lds, H1c, 0);
            compF<10>(lds, W1S, 1024, 512, colg * 160, acc);
            __syncthreads();
            u16* H1L = lds; u16* STL = lds + 4096;
#pragma unroll
            for (int mt = 0; mt < 2; ++mt)
#pragma unroll
                for (int dh = 0; dh < 2; ++dh)
#pragma unroll
                    for (int reg = 0; reg < 4; ++reg) {
                        int row = w * 32 + mt * 16 + lg * 4 + reg;
                        int dl = dh * 16 + r;
                        int d = colg * 32 + dl;
                        const float* p1r = P1 + ((size_t)t * 128 + row) * 2048;
                        float gi = acc[mt][0 + dh][reg] + p1r[d];
                        float gf = acc[mt][2 + dh][reg] + p1r[512 + d];
                        float gg = acc[mt][4 + dh][reg] + p1r[1024 + d];
                        float go = acc[mt][6 + dh][reg] + p1r[1536 + d];
                        float gs = acc[mt][8 + dh][reg] + PS[((size_t)t * 128 + row) * 512 + d];
                        int mi = (mt * 2 + dh) * 4 + reg;
                        float m1n = sigm(gf) * m1[mi] + sigm(gi) * tanh_(gg);
                        m1[mi] = m1n;
                        float tm = tanh_(m1n);
                        H1L[row * 32 + dl] = f2bf(sigm(go) * tm);
                        STL[row * 32 + dl] = f2bf(sigm(gs) * tm);
                    }
            __syncthreads();
#pragma unroll
            for (int p = 0; p < 2; ++p) {
                int idx = p * 256 + tid;
                i32x4 v1 = *(const i32x4*)(H1L + idx * 8);
                st16x(H1n + (size_t)colg * 4096 + idx * 8, v1);
                i32x4 v2 = *(const i32x4*)(STL + idx * 8);
                st16x(STt + (size_t)colg * 4096 + idx * 8, v2);
            }
        }
        grid_barrier(bar, bi++);

        // ---- Ph2: g2p (16..31, reg-parked) ; s2->sen (32..33) ; ht->hid (34..35) ----
        f32x4 g2acc[2][8] = {};
        if (bid >= 16 && bid < 32) {
            int colg = bid - 16;
            stageB<128>(lds, H1n, 0);
            compF<8>(lds, W2H, 1024, 0, colg * 128, g2acc);
            stageB<128>(lds, H2c, 0);
            compF<8>(lds, W2H, 1024, 512, colg * 128, g2acc);
        } else if (bid >= 32 && bid < 34) {
            chain64<0>((bid - 32) * 64, STt, AFFS, affs_b, WSB, ws_b, S2t, SENt, lds);
        } else if (bid >= 34 && bid < 36) {
            chain64<1>((bid - 34) * 64, H1n, AFFH, affh_b, WGB, wg_b, HTBt, HIDt, lds);
        }
        grid_barrier(bar, bi++);

        // ---- Ph3: attention (all 64 blocks, 2 batch rows each) ----
        p_attn(bid, VAB, SENt, HIDt, whw, whb, SPB, S2t, HTBt, CHHt, &sm.att);
        grid_barrier(bar, bi++);

        // ---- Ph4: att = tanh(chh @ wp^T + b) (blocks 32..33, row chain) ----
        if (bid >= 32 && bid < 34) {
            chain64<2>((bid - 32) * 64, CHHt, WPB, wp_b, (const u16*)0, (const float*)0,
                       ATTt, (float*)0, lds);
        }
        grid_barrier(bar, bi++);

        // ---- Ph5: LSTM2 (blocks 16..31, col; consumes register-parked g2acc) ----
        if (bid >= 16 && bid < 32) {
            int colg = bid - 16;
            stageL<128>(lds, ATTt);
            compF<8>(lds, W2A, 512, 0, colg * 128, g2acc);
            __syncthreads();
            u16* H2L = lds;
#pragma unroll
            for (int mt = 0; mt < 2; ++mt)
#pragma unroll
                for (int dh = 0; dh < 2; ++dh)
#pragma unroll
                    for (int reg = 0; reg < 4; ++reg) {
                        int row = w * 32 + mt * 16 + lg * 4 + reg;
                        int dl = dh * 16 + r;
                        int d = colg * 32 + dl;
                        float gi = g2acc[mt][0 + dh][reg] + b_ih2[d]        + b_hh2[d];
                        float gf = g2acc[mt][2 + dh][reg] + b_ih2[512 + d]  + b_hh2[512 + d];
                        float gg = g2acc[mt][4 + dh][reg] + b_ih2[1024 + d] + b_hh2[1024 + d];
                        float go = g2acc[mt][6 + dh][reg] + b_ih2[1536 + d] + b_hh2[1536 + d];
                        int mi = (mt * 2 + dh) * 4 + reg;
                        float m2n = sigm(gf) * m2[mi] + sigm(gi) * tanh_(gg);
                        m2[mi] = m2n;
                        H2L[row * 32 + dl] = f2bf(sigm(go) * tanh_(m2n));
                    }
            __syncthreads();
#pragma unroll
            for (int p = 0; p < 2; ++p) {
                int idx = p * 256 + tid;
                i32x4 v = *(const i32x4*)(H2L + idx * 8);
                st16x(H2n + (size_t)colg * 4096 + idx * 8, v);
            }
        }
        if (t < 48) grid_barrier(bar, bi++);
    }
}

// Final: preds[b][t][v] = H2[t+1] @ fc_w^T + fc_b   (H2 in blocked layout)
__global__ __launch_bounds__(256) void k_fc(const u16* __restrict__ H2R, const u16* __restrict__ FCB,
                                            const float* __restrict__ fc_b, float* __restrict__ out) {
    int bid = blockIdx.x;
    int ng = bid % 157, mg = bid / 157;
    int w = threadIdx.x >> 6, lane = threadIdx.x & 63, r = lane & 15, lg = lane >> 4;
    int m_base = w * 32;                      // row within the 128-row (t) tile
    int n_base = ng * 64;
    int nt = (10000 - n_base) / 16; if (nt > 4) nt = 4;
    const u16* A = H2R + (size_t)(mg + 1) * 65536;   // blocked [16][128][32]
    f32x4 acc[2][4] = {};
    for (int k0 = 0; k0 < 512; k0 += 32) {
        int kk = k0 + lg * 8;
        int slice = kk >> 5, off = kk & 31;
        bf16x8 a0 = *(const bf16x8*)(A + (size_t)slice * 4096 + (m_base + r) * 32 + off);
        bf16x8 a1 = *(const bf16x8*)(A + (size_t)slice * 4096 + (m_base + 16 + r) * 32 + off);
#pragma unroll
        for (int j = 0; j < 4; ++j) {
            if (j < nt) {
                bf16x8 wf = *(const bf16x8*)(FCB + (size_t)(n_base + j * 16 + r) * 512 + kk);
                acc[0][j] = MFMA16(a0, wf, acc[0][j]);
                acc[1][j] = MFMA16(a1, wf, acc[1][j]);
            }
        }
    }
#pragma unroll
    for (int mt = 0; mt < 2; ++mt)
#pragma unroll
        for (int j = 0; j < 4; ++j) {
            if (j < nt) {
#pragma unroll
                for (int reg = 0; reg < 4; ++reg) {
                    int brow = m_base + mt * 16 + lg * 4 + reg;
                    int col = n_base + j * 16 + r;
                    out[((size_t)brow * 49 + mg) * 10000 + col] = acc[mt][j][reg] + fc_b[col];
                }
            }
        }
}

// ---------------------------------------------------------------------------

extern "C" void kernel_launch(void* const* d_in, const int* in_sizes, int n_in,
                              void* d_out, int out_size, void* d_ws, size_t ws_size,
                              hipStream_t stream) {
    (void)in_sizes; (void)n_in; (void)out_size; (void)ws_size;

    const float* SF      = (const float*)d_in[0];
    const float* GIMG    = (const float*)d_in[1];
    const int*   CAP     = (const int*)d_in[2];
    const float* EMB     = (const float*)d_in[4];
    const float* w_ih1   = (const float*)d_in[5];
    const float* w_hh1   = (const float*)d_in[6];
    const float* b_ih1   = (const float*)d_in[7];
    const float* b_hh1   = (const float*)d_in[8];
    const float* s_wx    = (const float*)d_in[9];
    const float* s_bx    = (const float*)d_in[10];
    const float* s_wh    = (const float*)d_in[11];
    const float* s_bh    = (const float*)d_in[12];
    const float* w_ih2   = (const float*)d_in[13];
    const float* w_hh2   = (const float*)d_in[14];
    const float* b_ih2   = (const float*)d_in[15];
    const float* b_hh2   = (const float*)d_in[16];
    const float* aff_s_w = (const float*)d_in[17];
    const float* aff_s_b = (const float*)d_in[18];
    const float* aff_h_w = (const float*)d_in[19];
    const float* aff_h_b = (const float*)d_in[20];
    const float* ws_w    = (const float*)d_in[21];
    const float* ws_b    = (const float*)d_in[22];
    const float* wg_w    = (const float*)d_in[23];
    const float* wg_b    = (const float*)d_in[24];
    const float* wv_w    = (const float*)d_in[25];
    const float* wv_b    = (const float*)d_in[26];
    const float* wh_w    = (const float*)d_in[27];
    const float* wh_b    = (const float*)d_in[28];
    const float* wp_w    = (const float*)d_in[29];
    const float* wp_b    = (const float*)d_in[30];
    const float* fc_w    = (const float*)d_in[31];
    const float* fc_b    = (const float*)d_in[32];

    float* out = (float*)d_out;

    // fp32 scratch in d_out (fc overwrites all of d_out at the end):
    float* P1 = out;                       // 49*128*2048 floats
    float* PS = out + 12845056;            //  3,211,264 floats
    u16*  XWB = (u16*)(out + 17000000);    //  6,422,528 u16 (consumed before scan)
    // rotating per-step buffers (scan-only; fc overwrites later):
    u16*   H1R  = (u16*)(out + 21000000);  // 50*65536 u16, blocked
    u16*   STR  = (u16*)(out + 22700000);  // 49*65536 u16, blocked
    u16*   S2R  = (u16*)(out + 24400000);  // [row][512]
    u16*   HTBR = (u16*)(out + 26100000);
    u16*   CHHR = (u16*)(out + 27800000);
    u16*   ATTR = (u16*)(out + 29500000);
    float* SENR = out + 31200000;          // 49*65536 f32
    float* HIDR = out + 34500000;          // ends ~37.7M < 62.72M

    char* ws = (char*)d_ws;
    size_t off = 0;
    auto alloc = [&](size_t elts, size_t esz) -> void* {
        void* p = ws + off;
        off += (elts * esz + 255) & ~(size_t)255;
        return p;
    };
    u16* W1S   = (u16*)alloc(2621440, 2);
    u16* W2H   = (u16*)alloc(2097152, 2);
    u16* W2A   = (u16*)alloc(1048576, 2);
    u16* W1X   = (u16*)alloc(2097152, 2);
    u16* WSX   = (u16*)alloc(524288, 2);
    u16* AFFS  = (u16*)alloc(262144, 2);
    u16* AFFH  = (u16*)alloc(262144, 2);
    u16* WSB   = (u16*)alloc(262144, 2);
    u16* WGB   = (u16*)alloc(262144, 2);
    u16* WVB   = (u16*)alloc(262144, 2);
    u16* WPB   = (u16*)alloc(262144, 2);
    u16* FCB   = (u16*)alloc(5120000, 2);
    u16* SPB   = (u16*)alloc(3211264, 2);
    u16* VAB   = (u16*)alloc(3211264, 2);
    u16* H2R   = (u16*)alloc(3276800, 2);  // 50*65536 u16, blocked (read by k_fc)
    int* BAR   = (int*)alloc(2048, 4);

    // zero-init step-0 state + barrier counters (every call / replay)
    hipMemsetAsync(H1R, 0, 65536 * 2, stream);
    hipMemsetAsync(H2R, 0, 65536 * 2, stream);
    hipMemsetAsync(BAR, 0, 2048 * 4, stream);

    // prep: conversions + packs + xw gather
    k_cvt8<<<38688, 256, 0, stream>>>(aff_s_w, aff_h_w, ws_w, wg_w, wv_w, wp_w, fc_w, SF,
                                      AFFS, AFFH, WSB, WGB, WVB, WPB, FCB, SPB);
    k_packX<<<(2621440 + 255) / 256, 256, 0, stream>>>(w_ih1, s_wx, W1X, WSX);
    k_packS<<<(5767168 + 255) / 256, 256, 0, stream>>>(w_ih1, w_hh1, s_wx, s_wh, w_ih2, w_hh2,
                                                       W1S, W2H, W2A);
    k_xw<<<(6422528 + 255) / 256, 256, 0, stream>>>(EMB, GIMG, CAP, XWB, 6422528);

    // batched precompute GEMMs
    k_p1ps<<<49 * 40, 256, 0, stream>>>(XWB, W1X, WSX, b_ih1, b_hh1, s_bx, s_bh, P1, PS);
    k_va<<<49 * 8, 256, 0, stream>>>(SPB, WVB, wv_b, VAB);

    // persistent sequential scan (64 co-resident blocks, fence-free barriers)
    k_scan<<<NBLK, 256, 0, stream>>>(W1S, W2H, W2A, AFFS, AFFH, WSB, WGB, WPB,
                                     P1, PS, VAB, SPB, b_ih2, b_hh2, aff_s_b, aff_h_b,
                                     wg_b, ws_b, wp_b, wh_w, wh_b,
                                     H1R, H2R, STR, S2R, HTBR, CHHR, ATTR,
                                     SENR, HIDR, BAR);

    // final projection to vocab
    k_fc<<<49 * 157, 256, 0, stream>>>(H2R, FCB, fc_b, out);
}

// Round 9
// 14078.448 us; speedup vs baseline: 3.2961x; 3.2195x over previous
//
#include <hip/hip_runtime.h>

// ---------------------------------------------------------------------------
// Adaptive-attention LSTM decoder (B=128, P=49, D=E=A=512, V=10000, T=50).
// MULTI-LAUNCH scan (R1 structure, verified 6.97ms), fused to 4 kernels/step:
//   k_lstm1 (col-par, 32 blk) -> k_ph23 (g2p col 32 blk + s2->sen / ht->hid
//   row-chains 8 blk) -> k_attwp (attn + wp GEMM fused, 16 blk x 8 rows)
//   -> k_lstm2 (col-par, 32 blk).
// Inter-kernel coherence comes from kernel boundaries (normal cached ld/st,
// write-back L2) - the persistent-kernel experiments (R3-R8) proved coherent
// bypass traffic runs latency-bound at <100 GB/s and cannot win.
// All GEMMs bf16 MFMA 16x16x32, fp32 accum. m1/m2 fp32. VA/SF bf16 in attn.
// ---------------------------------------------------------------------------

typedef unsigned short u16;
typedef short bf16x8 __attribute__((ext_vector_type(8)));
typedef float f32x4 __attribute__((ext_vector_type(4)));

#define MFMA16(a, b, c) __builtin_amdgcn_mfma_f32_16x16x32_bf16(a, b, c, 0, 0, 0)

__device__ __forceinline__ u16 f2bf(float f) {
    union { float f; unsigned u; } v; v.f = f;
    return (u16)((v.u + 0x7fffu + ((v.u >> 16) & 1u)) >> 16);
}
__device__ __forceinline__ float bf2f(u16 h) {
    union { unsigned u; float f; } v; v.u = ((unsigned)h) << 16; return v.f;
}
__device__ __forceinline__ float sigm(float x) {
    x = fminf(fmaxf(x, -30.f), 30.f);
    return 1.f / (1.f + __expf(-x));
}
__device__ __forceinline__ float tanh_(float x) {
    x = fminf(fmaxf(x, -15.f), 15.f);
    float e = __expf(2.f * x);
    return (e - 1.f) / (e + 1.f);
}

// Wave computes 2 m-tiles x up to NT n-tiles of C = A @ W^T.
// A: [M][K] bf16 row-major, optionally split in K at `asplit` (A0 then A1).
// W: [N][K] bf16 row-major. K, asplit multiples of 32.
template<int NT>
__device__ __forceinline__ void gemmN(const u16* __restrict__ A0, const u16* __restrict__ A1,
                                      int asplit, int lda0, int lda1,
                                      const u16* __restrict__ W, int ldw, int K,
                                      int m_base, int n_base, int nt, f32x4 acc[2][NT]) {
    const int lane = threadIdx.x & 63, r = lane & 15, lg = lane >> 4;
    for (int k0 = 0; k0 < K; k0 += 32) {
        int kk = k0 + lg * 8;
        const u16* Ab; int ka, lda;
        if (k0 < asplit) { Ab = A0; ka = kk; lda = lda0; }
        else             { Ab = A1; ka = kk - asplit; lda = lda1; }
        bf16x8 a0 = *(const bf16x8*)(Ab + (size_t)(m_base + r) * lda + ka);
        bf16x8 a1 = *(const bf16x8*)(Ab + (size_t)(m_base + 16 + r) * lda + ka);
#pragma unroll
        for (int j = 0; j < NT; ++j) {
            if (j < nt) {
                bf16x8 wf = *(const bf16x8*)(W + (size_t)(n_base + j * 16 + r) * ldw + kk);
                acc[0][j] = MFMA16(a0, wf, acc[0][j]);
                acc[1][j] = MFMA16(a1, wf, acc[1][j]);
            }
        }
    }
}

// ---------------- one-time conversion / packing kernels ----------------

__global__ __launch_bounds__(256) void k_cvt8(
    const float* __restrict__ s0, const float* __restrict__ s1, const float* __restrict__ s2,
    const float* __restrict__ s3, const float* __restrict__ s4, const float* __restrict__ s5,
    const float* __restrict__ s6, const float* __restrict__ s7,
    u16* __restrict__ d0, u16* __restrict__ d1, u16* __restrict__ d2, u16* __restrict__ d3,
    u16* __restrict__ d4, u16* __restrict__ d5, u16* __restrict__ d6, u16* __restrict__ d7) {
    int i = blockIdx.x * 256 + threadIdx.x;
    const int S = 262144;
    if (i < 6 * S) {
        int seg = i >> 18, off = i & (S - 1);
        const float* s = seg == 0 ? s0 : seg == 1 ? s1 : seg == 2 ? s2 : seg == 3 ? s3 : seg == 4 ? s4 : s5;
        u16* d = seg == 0 ? d0 : seg == 1 ? d1 : seg == 2 ? d2 : seg == 3 ? d3 : seg == 4 ? d4 : d5;
        d[off] = f2bf(s[off]);
    } else if (i < 6 * S + 5120000) {
        int off = i - 6 * S;
        d6[off] = f2bf(s6[off]);
    } else {
        int off = i - 6 * S - 5120000;
        if (off < 3211264) d7[off] = f2bf(s7[off]);
    }
}

// dst[n][k] = (k < wA) ? A[n*ldA + offA + k] : B[n*ldB + (k - wA)]
__device__ __forceinline__ void packel(const float* __restrict__ A, int ldA, int offA, int wA,
                                       const float* __restrict__ Bs, int ldB,
                                       u16* __restrict__ dst, int Ktot, int i) {
    int n = i / Ktot, k = i - n * Ktot;
    float v = (k < wA) ? A[(size_t)n * ldA + offA + k] : Bs[(size_t)n * ldB + (k - wA)];
    dst[i] = f2bf(v);
}

__global__ __launch_bounds__(256) void k_pack6(
    const float* __restrict__ w_ih1, const float* __restrict__ w_hh1,
    const float* __restrict__ s_wx, const float* __restrict__ s_wh,
    const float* __restrict__ w_ih2, const float* __restrict__ w_hh2,
    u16* __restrict__ W1H, u16* __restrict__ WSH, u16* __restrict__ W1X,
    u16* __restrict__ WSX, u16* __restrict__ W2A, u16* __restrict__ W2H) {
    int i = blockIdx.x * 256 + threadIdx.x;
    if      (i < 2097152) packel(w_ih1, 1536, 0, 512, w_hh1, 512, W1H, 1024, i);
    else if (i < 2621440) packel(s_wx, 1536, 0, 512, s_wh, 512, WSH, 1024, i - 2097152);
    else if (i < 4718592) packel(w_ih1, 1536, 512, 1024, w_ih1, 1536, W1X, 1024, i - 2621440);
    else if (i < 5242880) packel(s_wx, 1536, 512, 1024, s_wx, 1536, WSX, 1024, i - 4718592);
    else if (i < 6291456) packel(w_ih2, 1024, 0, 512, w_ih2, 1024, W2A, 512, i - 5242880);
    else if (i < 8388608) packel(w_ih2, 1024, 512, 512, w_hh2, 512, W2H, 1024, i - 6291456);
}

// xw[t][b][k] : k<512 -> emb[cap[b][t]][k], else global_image[b][k-512]
__global__ __launch_bounds__(256) void k_xw(const float* __restrict__ emb, const float* __restrict__ gimg,
                                            const int* __restrict__ cap, u16* __restrict__ XW, int total) {
    int i = blockIdx.x * 256 + threadIdx.x;
    if (i >= total) return;
    int t = i >> 17;
    int rem = i & ((1 << 17) - 1);
    int b = rem >> 10, k = rem & 1023;
    float v = (k < 512) ? emb[(size_t)cap[b * 50 + t] * 512 + k] : gimg[b * 512 + (k - 512)];
    XW[i] = f2bf(v);
}

// ---------------- batched precompute GEMMs ----------------

__global__ __launch_bounds__(256) void k_p1ps(const u16* __restrict__ XW, const u16* __restrict__ W1X,
                                              const u16* __restrict__ WSX,
                                              const float* __restrict__ b_ih1, const float* __restrict__ b_hh1,
                                              const float* __restrict__ s_bx, const float* __restrict__ s_bh,
                                              float* __restrict__ P1, float* __restrict__ PS) {
    int bid = blockIdx.x;
    int ng = bid % 40, mg = bid / 40;
    int w = threadIdx.x >> 6, lane = threadIdx.x & 63, r = lane & 15, lg = lane >> 4;
    int m_base = mg * 128 + w * 32;
    f32x4 acc[2][4] = {};
    if (ng < 32) {
        int n_base = ng * 64;
        gemmN<4>(XW, XW, 1 << 28, 1024, 1024, W1X, 1024, 1024, m_base, n_base, 4, acc);
#pragma unroll
        for (int mt = 0; mt < 2; ++mt)
#pragma unroll
            for (int j = 0; j < 4; ++j)
#pragma unroll
                for (int reg = 0; reg < 4; ++reg) {
                    int row = m_base + mt * 16 + lg * 4 + reg;
                    int col = n_base + j * 16 + r;
                    P1[(size_t)row * 2048 + col] = acc[mt][j][reg] + b_ih1[col] + b_hh1[col];
                }
    } else {
        int n_base = (ng - 32) * 64;
        gemmN<4>(XW, XW, 1 << 28, 1024, 1024, WSX, 1024, 1024, m_base, n_base, 4, acc);
#pragma unroll
        for (int mt = 0; mt < 2; ++mt)
#pragma unroll
            for (int j = 0; j < 4; ++j)
#pragma unroll
                for (int reg = 0; reg < 4; ++reg) {
                    int row = m_base + mt * 16 + lg * 4 + reg;
                    int col = n_base + j * 16 + r;
                    PS[(size_t)row * 512 + col] = acc[mt][j][reg] + s_bx[col] + s_bh[col];
                }
    }
}

__global__ __launch_bounds__(256) void k_va(const u16* __restrict__ SPB, const u16* __restrict__ WVB,
                                            const float* __restrict__ wv_b, u16* __restrict__ VAB) {
    int bid = blockIdx.x;
    int ng = bid % 8, mg = bid / 8;
    int w = threadIdx.x >> 6, lane = threadIdx.x & 63, r = lane & 15, lg = lane >> 4;
    int m_base = mg * 128 + w * 32;
    int n_base = ng * 64;
    f32x4 acc[2][4] = {};
    gemmN<4>(SPB, SPB, 1 << 28, 512, 512, WVB, 512, 512, m_base, n_base, 4, acc);
#pragma unroll
    for (int mt = 0; mt < 2; ++mt)
#pragma unroll
        for (int j = 0; j < 4; ++j)
#pragma unroll
            for (int reg = 0; reg < 4; ++reg) {
                int row = m_base + mt * 16 + lg * 4 + reg;
                int col = n_base + j * 16 + r;
                VAB[(size_t)row * 512 + col] = f2bf(acc[mt][j][reg] + wv_b[col]);
            }
}

// ---------------- per-step kernels (4 per step) ----------------

// Step kernel 1: LSTM1 gates + sentinel gate, fused cell update. (R1 verbatim)
__global__ __launch_bounds__(256) void k_lstm1(const u16* __restrict__ H2BF, const u16* __restrict__ H1C,
                                               const u16* __restrict__ W1H, const u16* __restrict__ WSH,
                                               const float* __restrict__ P1, const float* __restrict__ PS,
                                               float* __restrict__ M1, u16* __restrict__ H1N,
                                               u16* __restrict__ STBF, int t) {
    int d0 = blockIdx.x * 16;  // 32 blocks cover d = 0..511
    int w = threadIdx.x >> 6, lane = threadIdx.x & 63, r = lane & 15, lg = lane >> 4;
    int m_base = w * 32;
    f32x4 acc[2][5] = {};
    for (int k0 = 0; k0 < 1024; k0 += 32) {
        int kk = k0 + lg * 8;
        const u16* Ab = (k0 < 512) ? H2BF : H1C;
        int ka = (k0 < 512) ? kk : kk - 512;
        bf16x8 a0 = *(const bf16x8*)(Ab + (size_t)(m_base + r) * 512 + ka);
        bf16x8 a1 = *(const bf16x8*)(Ab + (size_t)(m_base + 16 + r) * 512 + ka);
#pragma unroll
        for (int gt = 0; gt < 4; ++gt) {
            bf16x8 wf = *(const bf16x8*)(W1H + (size_t)(gt * 512 + d0 + r) * 1024 + kk);
            acc[0][gt] = MFMA16(a0, wf, acc[0][gt]);
            acc[1][gt] = MFMA16(a1, wf, acc[1][gt]);
        }
        bf16x8 wsf = *(const bf16x8*)(WSH + (size_t)(d0 + r) * 1024 + kk);
        acc[0][4] = MFMA16(a0, wsf, acc[0][4]);
        acc[1][4] = MFMA16(a1, wsf, acc[1][4]);
    }
    int d = d0 + r;
#pragma unroll
    for (int mt = 0; mt < 2; ++mt)
#pragma unroll
        for (int reg = 0; reg < 4; ++reg) {
            int row = m_base + mt * 16 + lg * 4 + reg;
            const float* p1r = P1 + ((size_t)t * 128 + row) * 2048;
            float gi = acc[mt][0][reg] + p1r[d];
            float gf = acc[mt][1][reg] + p1r[512 + d];
            float gg = acc[mt][2][reg] + p1r[1024 + d];
            float go = acc[mt][3][reg] + p1r[1536 + d];
            float gs = acc[mt][4][reg] + PS[((size_t)t * 128 + row) * 512 + d];
            int idx = row * 512 + d;
            float m1o = M1[idx];
            float m1n = sigm(gf) * m1o + sigm(gi) * tanh_(gg);
            float h1n = sigm(go) * tanh_(m1n);
            float st  = sigm(gs) * tanh_(m1n);
            M1[idx] = m1n;
            H1N[idx] = f2bf(h1n);
            STBF[idx] = f2bf(st);
        }
}

// Step kernel 2: g2p (col-par, blocks 0..31) + s2->sen chain (32..35)
// + ht->hid chain (36..39). Chains are row-parallel (32 rows/block), GEMM2
// reads the block's own GEMM1 output (same-CU coherent after __syncthreads).
__global__ __launch_bounds__(256) void k_ph23(
    const u16* __restrict__ STBF, const u16* __restrict__ H1N, const u16* __restrict__ H2BF,
    const u16* __restrict__ W2H, const u16* __restrict__ AFFS, const u16* __restrict__ AFFH,
    const u16* __restrict__ WSB, const u16* __restrict__ WGB,
    const float* __restrict__ affs_b, const float* __restrict__ affh_b,
    const float* __restrict__ ws_b, const float* __restrict__ wg_b,
    u16* __restrict__ S2BF, float* __restrict__ SEN,
    float* __restrict__ HTF, u16* __restrict__ HTBF, float* __restrict__ HID,
    float* __restrict__ G2P) {
    int bid = blockIdx.x;
    int w = threadIdx.x >> 6, lane = threadIdx.x & 63, r = lane & 15, lg = lane >> 4;
    if (bid < 32) {
        int m_base = w * 32, n_base = bid * 64;
        f32x4 acc[2][4] = {};
        gemmN<4>(H1N, H2BF, 512, 512, 512, W2H, 1024, 1024, m_base, n_base, 4, acc);
#pragma unroll
        for (int mt = 0; mt < 2; ++mt)
#pragma unroll
            for (int j = 0; j < 4; ++j)
#pragma unroll
                for (int reg = 0; reg < 4; ++reg) {
                    int row = m_base + mt * 16 + lg * 4 + reg;
                    int col = n_base + j * 16 + r;
                    G2P[(size_t)row * 2048 + col] = acc[mt][j][reg];
                }
    } else {
        bool isS = bid < 36;
        int rowg = isS ? (bid - 32) : (bid - 36);
        int m_base = rowg * 32, n_base = w * 128;
        const u16* SRC = isS ? STBF : H1N;
        const u16* W1 = isS ? AFFS : AFFH;
        const float* b1 = isS ? affs_b : affh_b;
        {
            f32x4 acc[2][8] = {};
            gemmN<8>(SRC, SRC, 1 << 28, 512, 512, W1, 512, 512, m_base, n_base, 8, acc);
#pragma unroll
            for (int mt = 0; mt < 2; ++mt)
#pragma unroll
                for (int j = 0; j < 8; ++j)
#pragma unroll
                    for (int reg = 0; reg < 4; ++reg) {
                        int row = m_base + mt * 16 + lg * 4 + reg;
                        int col = n_base + j * 16 + r;
                        float v = acc[mt][j][reg] + b1[col];
                        if (isS) {
                            v = fmaxf(v, 0.f);
                            S2BF[row * 512 + col] = f2bf(v);
                        } else {
                            v = tanh_(v);
                            HTF[row * 512 + col] = v;
                            HTBF[row * 512 + col] = f2bf(v);
                        }
                    }
        }
        __syncthreads();   // own-block global RAW: stores drained, same-CU L1/L2 coherent
        const u16* MID = isS ? S2BF : HTBF;
        const u16* W2 = isS ? WSB : WGB;
        const float* b2 = isS ? ws_b : wg_b;
        float* OUT = isS ? SEN : HID;
        {
            f32x4 acc[2][8] = {};
            gemmN<8>(MID, MID, 1 << 28, 512, 512, W2, 512, 512, m_base, n_base, 8, acc);
#pragma unroll
            for (int mt = 0; mt < 2; ++mt)
#pragma unroll
                for (int j = 0; j < 8; ++j)
#pragma unroll
                    for (int reg = 0; reg < 4; ++reg) {
                        int row = m_base + mt * 16 + lg * 4 + reg;
                        int col = n_base + j * 16 + r;
                        OUT[row * 512 + col] = acc[mt][j][reg] + b2[col];
                    }
        }
    }
}

// Step kernel 3: attention + wp GEMM fused. 16 blocks x 8 batch rows.
// z/softmax/c_hat per row; chh kept in LDS (bf16); att = tanh(chh@wp^T+b).
__global__ __launch_bounds__(256) void k_attwp(
    const u16* __restrict__ VAB, const float* __restrict__ SEN, const float* __restrict__ HID,
    const float* __restrict__ whw, const float* __restrict__ whb,
    const u16* __restrict__ SPB, const u16* __restrict__ S2BF, const float* __restrict__ HTF,
    const u16* __restrict__ WPB, const float* __restrict__ wp_b, u16* __restrict__ ATTBF) {
    __shared__ float whwL[512];
    __shared__ float hidL[8][512];
    __shared__ float zb[8][52];
    __shared__ float alb[8][52];
    __shared__ u16 chhL[16][520];   // padded; rows 8..15 zero
    int b0 = blockIdx.x * 8;
    int tid = threadIdx.x;
    int w = tid >> 6, lane = tid & 63, r = lane & 15, lg = lane >> 4;
    for (int i = tid; i < 512; i += 256) whwL[i] = whw[i];
    for (int q = tid; q < 8 * 512; q += 256) {
        int lr = q >> 9, d = q & 511;
        hidL[lr][d] = HID[(size_t)(b0 + lr) * 512 + d];
    }
    for (int q = tid; q < 8 * 520; q += 256) {
        int lr = q / 520, c = q - lr * 520;
        chhL[8 + lr][c] = 0;
    }
    __syncthreads();
    // z for 8 rows x 50 positions
    for (int lr = 0; lr < 8; ++lr) {
        int b = b0 + lr;
        for (int p = w; p < 50; p += 4) {
            float part = 0.f;
            if (p < 49) {
                const u16* src = VAB + ((size_t)b * 49 + p) * 512;
#pragma unroll
                for (int it = 0; it < 8; ++it) {
                    int a = lane + it * 64;
                    part += tanh_(bf2f(src[a]) + hidL[lr][a]) * whwL[a];
                }
            } else {
#pragma unroll
                for (int it = 0; it < 8; ++it) {
                    int a = lane + it * 64;
                    part += tanh_(SEN[(size_t)b * 512 + a] + hidL[lr][a]) * whwL[a];
                }
            }
#pragma unroll
            for (int o = 32; o; o >>= 1) part += __shfl_xor(part, o, 64);
            if (lane == 0) zb[lr][p] = part + whb[0];
        }
    }
    __syncthreads();
    // softmax: wave w handles rows w and w+4
    for (int lr = w; lr < 8; lr += 4) {
        float v = (lane < 50) ? zb[lr][lane] : -1e30f;
        float mx = v;
#pragma unroll
        for (int o = 32; o; o >>= 1) mx = fmaxf(mx, __shfl_xor(mx, o, 64));
        float e = (lane < 50) ? __expf(v - mx) : 0.f;
        float s = e;
#pragma unroll
        for (int o = 32; o; o >>= 1) s += __shfl_xor(s, o, 64);
        if (lane < 50) alb[lr][lane] = e / s;
    }
    __syncthreads();
    // c_hat + ht -> chhL (bf16); each thread does 2 d per row
    {
        int d0 = tid * 2;
        for (int lr = 0; lr < 8; ++lr) {
            int b = b0 + lr;
            float a49 = alb[lr][49];
            unsigned s2p = *(const unsigned*)(S2BF + (size_t)b * 512 + d0);
            float acc0 = a49 * bf2f((u16)(s2p & 0xffffu));
            float acc1 = a49 * bf2f((u16)(s2p >> 16));
            for (int p = 0; p < 49; ++p) {
                unsigned q = *(const unsigned*)(SPB + ((size_t)b * 49 + p) * 512 + d0);
                float al = alb[lr][p];
                acc0 += al * bf2f((u16)(q & 0xffffu));
                acc1 += al * bf2f((u16)(q >> 16));
            }
            acc0 += HTF[(size_t)b * 512 + d0];
            acc1 += HTF[(size_t)b * 512 + d0 + 1];
            chhL[lr][d0] = f2bf(acc0);
            chhL[lr][d0 + 1] = f2bf(acc1);
        }
    }
    __syncthreads();
    // wp GEMM: one 16-row m-tile (8 valid rows), wave w covers cols w*128..+128
    {
        f32x4 acc[8] = {};
        for (int k0 = 0; k0 < 512; k0 += 32) {
            int kk = k0 + lg * 8;
            bf16x8 a = *(const bf16x8*)(&chhL[r][kk]);
#pragma unroll
            for (int j = 0; j < 8; ++j) {
                bf16x8 wf = *(const bf16x8*)(WPB + (size_t)(w * 128 + j * 16 + r) * 512 + kk);
                acc[j] = MFMA16(a, wf, acc[j]);
            }
        }
#pragma unroll
        for (int j = 0; j < 8; ++j)
#pragma unroll
            for (int reg = 0; reg < 4; ++reg) {
                int row = lg * 4 + reg;
                if (row < 8) {
                    int col = w * 128 + j * 16 + r;
                    ATTBF[(size_t)(b0 + row) * 512 + col] = f2bf(tanh_(acc[j][reg] + wp_b[col]));
                }
            }
    }
}

// Step kernel 4: LSTM2. (R1 verbatim)
__global__ __launch_bounds__(256) void k_lstm2(const u16* __restrict__ ATTBF, const u16* __restrict__ W2A,
                                               const float* __restrict__ G2P,
                                               const float* __restrict__ b_ih2, const float* __restrict__ b_hh2,
                                               float* __restrict__ M2, u16* __restrict__ H2BF,
                                               u16* __restrict__ H2ALL, int t) {
    int d0 = blockIdx.x * 16;
    int w = threadIdx.x >> 6, lane = threadIdx.x & 63, r = lane & 15, lg = lane >> 4;
    int m_base = w * 32;
    f32x4 acc[2][4] = {};
    for (int k0 = 0; k0 < 512; k0 += 32) {
        int kk = k0 + lg * 8;
        bf16x8 a0 = *(const bf16x8*)(ATTBF + (size_t)(m_base + r) * 512 + kk);
        bf16x8 a1 = *(const bf16x8*)(ATTBF + (size_t)(m_base + 16 + r) * 512 + kk);
#pragma unroll
        for (int gt = 0; gt < 4; ++gt) {
            bf16x8 wf = *(const bf16x8*)(W2A + (size_t)(gt * 512 + d0 + r) * 512 + kk);
            acc[0][gt] = MFMA16(a0, wf, acc[0][gt]);
            acc[1][gt] = MFMA16(a1, wf, acc[1][gt]);
        }
    }
    int d = d0 + r;
#pragma unroll
    for (int mt = 0; mt < 2; ++mt)
#pragma unroll
        for (int reg = 0; reg < 4; ++reg) {
            int row = m_base + mt * 16 + lg * 4 + reg;
            const float* g2r = G2P + (size_t)row * 2048;
            float gi = acc[mt][0][reg] + g2r[d]        + b_ih2[d]        + b_hh2[d];
            float gf = acc[mt][1][reg] + g2r[512 + d]  + b_ih2[512 + d]  + b_hh2[512 + d];
            float gg = acc[mt][2][reg] + g2r[1024 + d] + b_ih2[1024 + d] + b_hh2[1024 + d];
            float go = acc[mt][3][reg] + g2r[1536 + d] + b_ih2[1536 + d] + b_hh2[1536 + d];
            int idx = row * 512 + d;
            float m2n = sigm(gf) * M2[idx] + sigm(gi) * tanh_(gg);
            float h2n = sigm(go) * tanh_(m2n);
            M2[idx] = m2n;
            u16 hb = f2bf(h2n);
            H2BF[idx] = hb;
            H2ALL[((size_t)t * 128 + row) * 512 + d] = hb;
        }
}

// Final: preds[b][t][v] = H2all[t*128+b] @ fc_w^T + fc_b  (R1 verbatim)
__global__ __launch_bounds__(256) void k_fc(const u16* __restrict__ H2ALL, const u16* __restrict__ FCB,
                                            const float* __restrict__ fc_b, float* __restrict__ out) {
    int bid = blockIdx.x;
    int ng = bid % 157, mg = bid / 157;
    int w = threadIdx.x >> 6, lane = threadIdx.x & 63, r = lane & 15, lg = lane >> 4;
    int m_base = mg * 128 + w * 32;
    int n_base = ng * 64;
    int nt = (10000 - n_base) / 16; if (nt > 4) nt = 4;
    f32x4 acc[2][4] = {};
    gemmN<4>(H2ALL, H2ALL, 1 << 28, 512, 512, FCB, 512, 512, m_base, n_base, nt, acc);
#pragma unroll
    for (int mt = 0; mt < 2; ++mt)
#pragma unroll
        for (int j = 0; j < 4; ++j) {
            if (j < nt) {
#pragma unroll
                for (int reg = 0; reg < 4; ++reg) {
                    int row = m_base + mt * 16 + lg * 4 + reg;
                    int col = n_base + j * 16 + r;
                    int t = row >> 7, b = row & 127;
                    out[((size_t)b * 49 + t) * 10000 + col] = acc[mt][j][reg] + fc_b[col];
                }
            }
        }
}

// ---------------------------------------------------------------------------

extern "C" void kernel_launch(void* const* d_in, const int* in_sizes, int n_in,
                              void* d_out, int out_size, void* d_ws, size_t ws_size,
                              hipStream_t stream) {
    (void)in_sizes; (void)n_in; (void)out_size; (void)ws_size;

    const float* SF      = (const float*)d_in[0];
    const float* GIMG    = (const float*)d_in[1];
    const int*   CAP     = (const int*)d_in[2];
    const float* EMB     = (const float*)d_in[4];
    const float* w_ih1   = (const float*)d_in[5];
    const float* w_hh1   = (const float*)d_in[6];
    const float* b_ih1   = (const float*)d_in[7];
    const float* b_hh1   = (const float*)d_in[8];
    const float* s_wx    = (const float*)d_in[9];
    const float* s_bx    = (const float*)d_in[10];
    const float* s_wh    = (const float*)d_in[11];
    const float* s_bh    = (const float*)d_in[12];
    const float* w_ih2   = (const float*)d_in[13];
    const float* w_hh2   = (const float*)d_in[14];
    const float* b_ih2   = (const float*)d_in[15];
    const float* b_hh2   = (const float*)d_in[16];
    const float* aff_s_w = (const float*)d_in[17];
    const float* aff_s_b = (const float*)d_in[18];
    const float* aff_h_w = (const float*)d_in[19];
    const float* aff_h_b = (const float*)d_in[20];
    const float* ws_w    = (const float*)d_in[21];
    const float* ws_b    = (const float*)d_in[22];
    const float* wg_w    = (const float*)d_in[23];
    const float* wg_b    = (const float*)d_in[24];
    const float* wv_w    = (const float*)d_in[25];
    const float* wv_b    = (const float*)d_in[26];
    const float* wh_w    = (const float*)d_in[27];
    const float* wh_b    = (const float*)d_in[28];
    const float* wp_w    = (const float*)d_in[29];
    const float* wp_b    = (const float*)d_in[30];
    const float* fc_w    = (const float*)d_in[31];
    const float* fc_b    = (const float*)d_in[32];

    float* out = (float*)d_out;

    // big fp32 scratch in d_out (fc overwrites all of d_out at the end)
    float* P1 = out;                       // 49*128*2048 floats
    float* PS = out + 12845056;            //  3,211,264 floats
    u16*  XWB = (u16*)(out + 17000000);    //  6,422,528 u16 (consumed before scan)

    char* ws = (char*)d_ws;
    size_t off = 0;
    auto alloc = [&](size_t elts, size_t esz) -> void* {
        void* p = ws + off;
        off += (elts * esz + 255) & ~(size_t)255;
        return p;
    };
    u16* W1H   = (u16*)alloc(2097152, 2);
    u16* WSH   = (u16*)alloc(524288, 2);
    u16* W1X   = (u16*)alloc(2097152, 2);
    u16* WSX   = (u16*)alloc(524288, 2);
    u16* W2A   = (u16*)alloc(1048576, 2);
    u16* W2H   = (u16*)alloc(2097152, 2);
    u16* AFFS  = (u16*)alloc(262144, 2);
    u16* AFFH  = (u16*)alloc(262144, 2);
    u16* WSB   = (u16*)alloc(262144, 2);
    u16* WGB   = (u16*)alloc(262144, 2);
    u16* WVB   = (u16*)alloc(262144, 2);
    u16* WPB   = (u16*)alloc(262144, 2);
    u16* FCB   = (u16*)alloc(5120000, 2);
    u16* SPB   = (u16*)alloc(3211264, 2);
    u16* VAB   = (u16*)alloc(3211264, 2);
    u16* H2ALL = (u16*)alloc(3211264, 2);
    u16* H1A   = (u16*)alloc(65536, 2);
    u16* H1B   = (u16*)alloc(65536, 2);
    u16* H2BF  = (u16*)alloc(65536, 2);
    u16* STBF  = (u16*)alloc(65536, 2);
    u16* S2BF  = (u16*)alloc(65536, 2);
    u16* HTBF  = (u16*)alloc(65536, 2);
    u16* ATTBF = (u16*)alloc(65536, 2);
    float* M1  = (float*)alloc(65536, 4);
    float* M2  = (float*)alloc(65536, 4);
    float* HTF = (float*)alloc(65536, 4);
    float* HID = (float*)alloc(65536, 4);
    float* SEN = (float*)alloc(65536, 4);
    float* G2P = (float*)alloc(262144, 4);

    // zero-init recurrent state (every call; harness does not re-poison)
    hipMemsetAsync(H1A, 0, 65536 * 2, stream);
    hipMemsetAsync(H2BF, 0, 65536 * 2, stream);
    hipMemsetAsync(M1, 0, 65536 * 4, stream);
    hipMemsetAsync(M2, 0, 65536 * 4, stream);

    // prep: conversions + packs + xw gather
    k_cvt8<<<38688, 256, 0, stream>>>(aff_s_w, aff_h_w, ws_w, wg_w, wv_w, wp_w, fc_w, SF,
                                      AFFS, AFFH, WSB, WGB, WVB, WPB, FCB, SPB);
    k_pack6<<<32768, 256, 0, stream>>>(w_ih1, w_hh1, s_wx, s_wh, w_ih2, w_hh2,
                                       W1H, WSH, W1X, WSX, W2A, W2H);
    k_xw<<<(6422528 + 255) / 256, 256, 0, stream>>>(EMB, GIMG, CAP, XWB, 6422528);

    // batched precompute GEMMs
    k_p1ps<<<49 * 40, 256, 0, stream>>>(XWB, W1X, WSX, b_ih1, b_hh1, s_bx, s_bh, P1, PS);
    k_va<<<49 * 8, 256, 0, stream>>>(SPB, WVB, wv_b, VAB);

    // sequential scan: 4 kernels per step
    for (int t = 0; t < 49; ++t) {
        const u16* h1c = (t & 1) ? H1B : H1A;
        u16* h1n = (t & 1) ? H1A : H1B;
        k_lstm1<<<32, 256, 0, stream>>>(H2BF, h1c, W1H, WSH, P1, PS, M1, h1n, STBF, t);
        k_ph23<<<40, 256, 0, stream>>>(STBF, h1n, H2BF, W2H, AFFS, AFFH, WSB, WGB,
                                       aff_s_b, aff_h_b, ws_b, wg_b,
                                       S2BF, SEN, HTF, HTBF, HID, G2P);
        k_attwp<<<16, 256, 0, stream>>>(VAB, SEN, HID, wh_w, wh_b, SPB, S2BF, HTF,
                                        WPB, wp_b, ATTBF);
        k_lstm2<<<32, 256, 0, stream>>>(ATTBF, W2A, G2P, b_ih2, b_hh2, M2, H2BF, H2ALL, t);
    }

    // final projection to vocab
    k_fc<<<49 * 157, 256, 0, stream>>>(H2ALL, FCB, fc_b, out);
}